// Round 6
// baseline (561.515 us; speedup 1.0000x reference)
//
#include <hip/hip_runtime.h>
#include <math.h>

#define N_NODES 50000
#define E_EDGES 600000
#define D_DIM 128
#define OUT_DIM 40
#define N_ITERS 5
#define GAMMA_C 0.1f
#define EPS_C 0.1f
#define SCAN_BLOCKS 196          // 196*256 = 50176 >= N_NODES

typedef short v8s __attribute__((ext_vector_type(8)));   // 8 bf16 (4 VGPRs)
typedef float v4f __attribute__((ext_vector_type(4)));   // MFMA accumulator
typedef unsigned int uint;
typedef unsigned short ushort;

__device__ __forceinline__ ushort f2bf(float f) {        // RNE fp32->bf16
    union { float f; uint u; } v; v.f = f;
    uint u = v.u;
    uint r = 0x7fffu + ((u >> 16) & 1u);
    return (ushort)((u + r) >> 16);
}
__device__ __forceinline__ float bf2f(ushort h) {
    union { uint u; float f; } v; v.u = ((uint)h) << 16;
    return v.f;
}
__device__ __forceinline__ float bflo(uint u) {          // low bf16 of packed pair
    union { uint u; float f; } v; v.u = u << 16; return v.f;
}
__device__ __forceinline__ float bfhi(uint u) {          // high bf16 of packed pair
    union { uint u; float f; } v; v.u = u & 0xffff0000u; return v.f;
}

// ---------------------------------------------------------------------------
// Weight prep (once): WembH = bf16(W_emb);
// Wcat2[c][k] (row-stride 256): k<128 -> A[c][k]=Wanti[c][k]-Wanti[k][c]-g*I,
//                               k>=128 -> W_lin[c][k-128]
// conv = [xh | agg] @ Wcat2^T  (K=256)
// ---------------------------------------------------------------------------
__global__ __launch_bounds__(256) void prep_w_kernel(const float* __restrict__ Wemb,
                                                     const float* __restrict__ Wlin,
                                                     const float* __restrict__ Wanti,
                                                     ushort* __restrict__ WembH,
                                                     ushort* __restrict__ Wcat2H) {
    int i = blockIdx.x * 256 + threadIdx.x;              // 16384
    int r = i >> 7, c = i & 127;
    WembH[i] = f2bf(Wemb[i]);
    float a = Wanti[r * 128 + c] - Wanti[c * 128 + r];
    if (r == c) a -= GAMMA_C;
    Wcat2H[r * 256 + c]       = f2bf(a);
    Wcat2H[r * 256 + 128 + c] = f2bf(Wlin[r * 128 + c]);
}

// ---------------------------------------------------------------------------
// embed GEMM: x = x0 @ W_emb^T + b_emb  (fp32 in, writes fp32 x AND bf16 xh)
// Tile 128x128, 4 waves, K=128 staged, XOR-swizzled conflict-free LDS.
// Fragments (verified m89/m120): A[m=lane&15][k=quad*8+j],
// B[n=lane&15][k=quad*8+j], C/D: col=lane&15, row=quad*4+reg.
// ---------------------------------------------------------------------------
__global__ __launch_bounds__(256) void mfma_embed_gemm(const float* __restrict__ Xf,
                                                       const ushort* __restrict__ Wh,
                                                       const float* __restrict__ bias,
                                                       float* __restrict__ xF,
                                                       ushort* __restrict__ xH,
                                                       int M) {
    __shared__ ushort Xs[128 * 128];
    __shared__ ushort Ws[128 * 128];
    const int tid = threadIdx.x;
    const int rowBase = blockIdx.x * 128;

#pragma unroll
    for (int p = 0; p < 8; ++p) {
        int cid = p * 256 + tid;
        int r = cid >> 4, c8 = cid & 15;
        int gr = rowBase + r;
        uint4 val = make_uint4(0, 0, 0, 0);
        if (gr < M) {
            const float* ptr = Xf + (size_t)gr * 128 + c8 * 8;
            float4 f0 = *(const float4*)ptr;
            float4 f1 = *(const float4*)(ptr + 4);
            val.x = (uint)f2bf(f0.x) | ((uint)f2bf(f0.y) << 16);
            val.y = (uint)f2bf(f0.z) | ((uint)f2bf(f0.w) << 16);
            val.z = (uint)f2bf(f1.x) | ((uint)f2bf(f1.y) << 16);
            val.w = (uint)f2bf(f1.z) | ((uint)f2bf(f1.w) << 16);
        }
        *(uint4*)(Xs + r * 128 + ((c8 ^ (r & 7)) << 3)) = val;
        uint4 wv = *(const uint4*)(Wh + (size_t)r * 128 + c8 * 8);
        *(uint4*)(Ws + r * 128 + ((c8 ^ (r & 7)) << 3)) = wv;
    }
    __syncthreads();

    const int lane = tid & 63;
    const int wv = tid >> 6;
    const int wrow = (wv & 1) * 64;
    const int wcol = (wv >> 1) * 64;
    const int l16 = lane & 15;
    const int q = lane >> 4;

    v4f acc[4][4];
#pragma unroll
    for (int i = 0; i < 4; ++i)
#pragma unroll
        for (int j = 0; j < 4; ++j) {
            v4f z = {0.f, 0.f, 0.f, 0.f};
            acc[i][j] = z;
        }

#pragma unroll
    for (int ks = 0; ks < 4; ++ks) {
        const int chunk = ks * 4 + q;
        v8s a[4], b[4];
#pragma unroll
        for (int i = 0; i < 4; ++i) {
            int m = wrow + i * 16 + l16;
            a[i] = *(const v8s*)(Xs + m * 128 + ((chunk ^ (m & 7)) << 3));
        }
#pragma unroll
        for (int j = 0; j < 4; ++j) {
            int n = wcol + j * 16 + l16;
            b[j] = *(const v8s*)(Ws + n * 128 + ((chunk ^ (n & 7)) << 3));
        }
#pragma unroll
        for (int i = 0; i < 4; ++i)
#pragma unroll
            for (int j = 0; j < 4; ++j)
                acc[i][j] = __builtin_amdgcn_mfma_f32_16x16x32_bf16(a[i], b[j], acc[i][j], 0, 0, 0);
    }

#pragma unroll
    for (int j = 0; j < 4; ++j) {
        int col = wcol + j * 16 + l16;
        float bj = bias[col];
#pragma unroll
        for (int i = 0; i < 4; ++i) {
            int grB = rowBase + wrow + i * 16 + q * 4;
#pragma unroll
            for (int r = 0; r < 4; ++r) {
                int gr = grB + r;
                if (gr < M) {
                    float v = acc[i][j][r] + bj;
                    xF[(size_t)gr * 128 + col] = v;
                    xH[(size_t)gr * 128 + col] = f2bf(v);
                }
            }
        }
    }
}

// ---------------------------------------------------------------------------
// FUSED per-iteration kernel:
//   agg[r]  = sum_e w_e * xhOld[src_e]        (gather -> LDS, 16 lanes/node)
//   conv    = xhOld@A^T + agg@W_lin^T + b     (two K=128 MFMA chunks)
//   x      += eps*tanh(conv); xhNew = bf16(x) (epilogue)
// xh ping-pong removes the gather/update race (gather reads xhOld only).
// ---------------------------------------------------------------------------
__global__ __launch_bounds__(256) void mfma_conv_gather_update(
        const ushort* __restrict__ xhOld, const int2* __restrict__ es2,
        const int* __restrict__ rowStart, const int* __restrict__ rowEnd,
        const ushort* __restrict__ Wcat2, const float* __restrict__ bconv,
        float* __restrict__ xF, ushort* __restrict__ xhNew, int M) {
    __shared__ ushort Xs[128 * 128];
    __shared__ ushort Ws[128 * 128];
    const int tid = threadIdx.x;
    const int rowBase = blockIdx.x * 128;

    // ---- stage Ws = W_lin chunk (k in [128,256)) ----
#pragma unroll
    for (int p = 0; p < 8; ++p) {
        int cid = p * 256 + tid;
        int r = cid >> 4, c8 = cid & 15;
        uint4 wv4 = *(const uint4*)(Wcat2 + (size_t)r * 256 + 128 + c8 * 8);
        *(uint4*)(Ws + r * 128 + ((c8 ^ (r & 7)) << 3)) = wv4;
    }

    // ---- gather agg rows directly into Xs (bf16, swizzled) ----
    {
        const int g = tid >> 4;           // node-group 0..15
        const int l = tid & 15;           // lane-in-group: elems [l*8, l*8+8)
        for (int n = 0; n < 8; ++n) {
            int r = n * 16 + g;           // row in tile
            int node = rowBase + r;
            float s[8] = {0.f, 0.f, 0.f, 0.f, 0.f, 0.f, 0.f, 0.f};
            if (node < M) {
                int e = rowStart[node], end = rowEnd[node];
                for (; e + 4 <= end; e += 4) {
                    int2 m0 = es2[e], m1 = es2[e + 1], m2 = es2[e + 2], m3 = es2[e + 3];
                    uint4 v0 = *(const uint4*)(xhOld + (size_t)m0.x * 128 + l * 8);
                    uint4 v1 = *(const uint4*)(xhOld + (size_t)m1.x * 128 + l * 8);
                    uint4 v2 = *(const uint4*)(xhOld + (size_t)m2.x * 128 + l * 8);
                    uint4 v3 = *(const uint4*)(xhOld + (size_t)m3.x * 128 + l * 8);
                    float w0 = __int_as_float(m0.y), w1 = __int_as_float(m1.y);
                    float w2 = __int_as_float(m2.y), w3 = __int_as_float(m3.y);
                    s[0] = fmaf(w0, bflo(v0.x), s[0]); s[1] = fmaf(w0, bfhi(v0.x), s[1]);
                    s[2] = fmaf(w0, bflo(v0.y), s[2]); s[3] = fmaf(w0, bfhi(v0.y), s[3]);
                    s[4] = fmaf(w0, bflo(v0.z), s[4]); s[5] = fmaf(w0, bfhi(v0.z), s[5]);
                    s[6] = fmaf(w0, bflo(v0.w), s[6]); s[7] = fmaf(w0, bfhi(v0.w), s[7]);
                    s[0] = fmaf(w1, bflo(v1.x), s[0]); s[1] = fmaf(w1, bfhi(v1.x), s[1]);
                    s[2] = fmaf(w1, bflo(v1.y), s[2]); s[3] = fmaf(w1, bfhi(v1.y), s[3]);
                    s[4] = fmaf(w1, bflo(v1.z), s[4]); s[5] = fmaf(w1, bfhi(v1.z), s[5]);
                    s[6] = fmaf(w1, bflo(v1.w), s[6]); s[7] = fmaf(w1, bfhi(v1.w), s[7]);
                    s[0] = fmaf(w2, bflo(v2.x), s[0]); s[1] = fmaf(w2, bfhi(v2.x), s[1]);
                    s[2] = fmaf(w2, bflo(v2.y), s[2]); s[3] = fmaf(w2, bfhi(v2.y), s[3]);
                    s[4] = fmaf(w2, bflo(v2.z), s[4]); s[5] = fmaf(w2, bfhi(v2.z), s[5]);
                    s[6] = fmaf(w2, bflo(v2.w), s[6]); s[7] = fmaf(w2, bfhi(v2.w), s[7]);
                    s[0] = fmaf(w3, bflo(v3.x), s[0]); s[1] = fmaf(w3, bfhi(v3.x), s[1]);
                    s[2] = fmaf(w3, bflo(v3.y), s[2]); s[3] = fmaf(w3, bfhi(v3.y), s[3]);
                    s[4] = fmaf(w3, bflo(v3.z), s[4]); s[5] = fmaf(w3, bfhi(v3.z), s[5]);
                    s[6] = fmaf(w3, bflo(v3.w), s[6]); s[7] = fmaf(w3, bfhi(v3.w), s[7]);
                }
                for (; e < end; ++e) {
                    int2 m = es2[e];
                    float w = __int_as_float(m.y);
                    uint4 v = *(const uint4*)(xhOld + (size_t)m.x * 128 + l * 8);
                    s[0] = fmaf(w, bflo(v.x), s[0]); s[1] = fmaf(w, bfhi(v.x), s[1]);
                    s[2] = fmaf(w, bflo(v.y), s[2]); s[3] = fmaf(w, bfhi(v.y), s[3]);
                    s[4] = fmaf(w, bflo(v.z), s[4]); s[5] = fmaf(w, bfhi(v.z), s[5]);
                    s[6] = fmaf(w, bflo(v.w), s[6]); s[7] = fmaf(w, bfhi(v.w), s[7]);
                }
            }
            uint4 o;
            o.x = (uint)f2bf(s[0]) | ((uint)f2bf(s[1]) << 16);
            o.y = (uint)f2bf(s[2]) | ((uint)f2bf(s[3]) << 16);
            o.z = (uint)f2bf(s[4]) | ((uint)f2bf(s[5]) << 16);
            o.w = (uint)f2bf(s[6]) | ((uint)f2bf(s[7]) << 16);
            *(uint4*)(Xs + r * 128 + ((l ^ (r & 7)) << 3)) = o;
        }
    }
    __syncthreads();

    const int lane = tid & 63;
    const int wv = tid >> 6;
    const int wrow = (wv & 1) * 64;
    const int wcol = (wv >> 1) * 64;
    const int l16 = lane & 15;
    const int q = lane >> 4;

    v4f acc[4][4];
#pragma unroll
    for (int i = 0; i < 4; ++i)
#pragma unroll
        for (int j = 0; j < 4; ++j) {
            v4f z = {0.f, 0.f, 0.f, 0.f};
            acc[i][j] = z;
        }

    // ---- MFMA chunk: agg @ W_lin^T ----
#pragma unroll
    for (int ks = 0; ks < 4; ++ks) {
        const int chunk = ks * 4 + q;
        v8s a[4], b[4];
#pragma unroll
        for (int i = 0; i < 4; ++i) {
            int m = wrow + i * 16 + l16;
            a[i] = *(const v8s*)(Xs + m * 128 + ((chunk ^ (m & 7)) << 3));
        }
#pragma unroll
        for (int j = 0; j < 4; ++j) {
            int n = wcol + j * 16 + l16;
            b[j] = *(const v8s*)(Ws + n * 128 + ((chunk ^ (n & 7)) << 3));
        }
#pragma unroll
        for (int i = 0; i < 4; ++i)
#pragma unroll
            for (int j = 0; j < 4; ++j)
                acc[i][j] = __builtin_amdgcn_mfma_f32_16x16x32_bf16(a[i], b[j], acc[i][j], 0, 0, 0);
    }
    __syncthreads();

    // ---- restage: Xs = xhOld own rows, Ws = A chunk (k in [0,128)) ----
#pragma unroll
    for (int p = 0; p < 8; ++p) {
        int cid = p * 256 + tid;
        int r = cid >> 4, c8 = cid & 15;
        int gr = rowBase + r;
        uint4 xv = make_uint4(0, 0, 0, 0);
        if (gr < M) xv = *(const uint4*)(xhOld + (size_t)gr * 128 + c8 * 8);
        *(uint4*)(Xs + r * 128 + ((c8 ^ (r & 7)) << 3)) = xv;
        uint4 wv4 = *(const uint4*)(Wcat2 + (size_t)r * 256 + c8 * 8);
        *(uint4*)(Ws + r * 128 + ((c8 ^ (r & 7)) << 3)) = wv4;
    }
    __syncthreads();

    // ---- MFMA chunk: xh @ A^T (accumulate) ----
#pragma unroll
    for (int ks = 0; ks < 4; ++ks) {
        const int chunk = ks * 4 + q;
        v8s a[4], b[4];
#pragma unroll
        for (int i = 0; i < 4; ++i) {
            int m = wrow + i * 16 + l16;
            a[i] = *(const v8s*)(Xs + m * 128 + ((chunk ^ (m & 7)) << 3));
        }
#pragma unroll
        for (int j = 0; j < 4; ++j) {
            int n = wcol + j * 16 + l16;
            b[j] = *(const v8s*)(Ws + n * 128 + ((chunk ^ (n & 7)) << 3));
        }
#pragma unroll
        for (int i = 0; i < 4; ++i)
#pragma unroll
            for (int j = 0; j < 4; ++j)
                acc[i][j] = __builtin_amdgcn_mfma_f32_16x16x32_bf16(a[i], b[j], acc[i][j], 0, 0, 0);
    }

    // ---- epilogue: x += eps*tanh(conv); xhNew = bf16(x) ----
#pragma unroll
    for (int j = 0; j < 4; ++j) {
        int col = wcol + j * 16 + l16;
        float bj = bconv[col];
#pragma unroll
        for (int i = 0; i < 4; ++i) {
            int grB = rowBase + wrow + i * 16 + q * 4;
#pragma unroll
            for (int r = 0; r < 4; ++r) {
                int gr = grB + r;
                if (gr < M) {
                    size_t off = (size_t)gr * 128 + col;
                    float conv = acc[i][j][r] + bj;
                    float xv = xF[off] + EPS_C * tanhf(conv);
                    xF[off] = xv;
                    xhNew[off] = f2bf(xv);
                }
            }
        }
    }
}

// ---------------------------------------------------------------------------
// CSR build (once per launch; edge structure is iteration-invariant)
// ---------------------------------------------------------------------------
__global__ __launch_bounds__(256) void zero_int_kernel(int* __restrict__ p, int n) {
    int i = blockIdx.x * 256 + threadIdx.x;
    if (i < n) p[i] = 0;
}

__global__ __launch_bounds__(256) void hist_kernel(const int* __restrict__ dst,
                                                   int* __restrict__ cnt) {
    int e = blockIdx.x * 256 + threadIdx.x;
    if (e < E_EDGES) atomicAdd(&cnt[dst[e]], 1);
}

__global__ __launch_bounds__(256) void scan_phase1(const int* __restrict__ deg,
                                                   int* __restrict__ localEx,
                                                   int* __restrict__ blockSums) {
    __shared__ int tmp[256];
    const int t = threadIdx.x;
    const int i = blockIdx.x * 256 + t;
    int v = (i < N_NODES) ? deg[i] : 0;
    tmp[t] = v;
    __syncthreads();
#pragma unroll
    for (int off = 1; off < 256; off <<= 1) {
        int u = (t >= off) ? tmp[t - off] : 0;
        __syncthreads();
        tmp[t] += u;
        __syncthreads();
    }
    if (i < N_NODES) localEx[i] = tmp[t] - v;
    if (t == 255) blockSums[blockIdx.x] = tmp[255];
}

__global__ __launch_bounds__(256) void scan_phase2(int* __restrict__ blockSums) {
    __shared__ int tmp[256];
    const int t = threadIdx.x;
    int v = (t < SCAN_BLOCKS) ? blockSums[t] : 0;
    tmp[t] = v;
    __syncthreads();
#pragma unroll
    for (int off = 1; off < 256; off <<= 1) {
        int u = (t >= off) ? tmp[t - off] : 0;
        __syncthreads();
        tmp[t] += u;
        __syncthreads();
    }
    if (t < SCAN_BLOCKS) blockSums[t] = tmp[t] - v;
}

__global__ __launch_bounds__(256) void scan_phase3(int* __restrict__ rowStart,
                                                   const int* __restrict__ blockSums,
                                                   int* __restrict__ cursor) {
    const int i = blockIdx.x * 256 + threadIdx.x;
    if (i >= N_NODES) return;
    int v = rowStart[i] + blockSums[blockIdx.x];
    rowStart[i] = v;
    cursor[i] = v;
}

// scatter edges into CSR order, packed {src, bits(w)}: one 8B store/edge
__global__ __launch_bounds__(256) void build_kernel(const int* __restrict__ src,
                                                    const int* __restrict__ dst,
                                                    const float* __restrict__ ew,
                                                    int* __restrict__ cursor,
                                                    int2* __restrict__ es2) {
    int e = blockIdx.x * 256 + threadIdx.x;
    if (e >= E_EDGES) return;
    int d = dst[e];
    int pos = atomicAdd(&cursor[d], 1);
    es2[pos] = make_int2(src[e], __float_as_int(ew[e]));
}

// ---------------------------------------------------------------------------
// Readout: out = x @ W_out^T + b_out (fp32, swizzled LDS, conflict-free)
// ---------------------------------------------------------------------------
__global__ __launch_bounds__(256) void out_gemm(const float* __restrict__ X,
                                                const float* __restrict__ W,
                                                const float* __restrict__ bias,
                                                float* __restrict__ C, int M) {
    __shared__ float Xs[64 * 128];
    __shared__ float Ws[64 * 128];
    const int tid = threadIdx.x;
    const int rowBase = blockIdx.x * 64;

#pragma unroll
    for (int p = 0; p < 8; ++p) {
        int fi = p * 256 + tid;
        int r = fi >> 5, c4 = fi & 31;
        int gr = rowBase + r;
        float4 v = make_float4(0.f, 0.f, 0.f, 0.f);
        if (gr < M) v = *(const float4*)(X + (size_t)gr * 128 + c4 * 4);
        *(float4*)(Xs + r * 128 + ((c4 ^ ((r >> 2) & 7)) << 2)) = v;
    }
#pragma unroll
    for (int p = 0; p < 8; ++p) {
        int fi = p * 256 + tid;
        int r = fi >> 5, c4 = fi & 31;
        float4 v = make_float4(0.f, 0.f, 0.f, 0.f);
        if (r < OUT_DIM) v = *(const float4*)(W + (size_t)r * 128 + c4 * 4);
        *(float4*)(Ws + r * 128 + ((c4 ^ ((r >> 2) & 7)) << 2)) = v;
    }
    __syncthreads();

    const int tx = tid & 15, ty = tid >> 4;
    const int r0 = ty * 4, c0 = tx * 4;
    const int swx = ty & 7, swy = tx & 7;

    float acc[4][4] = {};
#pragma unroll 8
    for (int k4 = 0; k4 < 32; ++k4) {
        const int cox = (k4 ^ swx) << 2;
        const int cow = (k4 ^ swy) << 2;
        float4 a[4], b[4];
#pragma unroll
        for (int i = 0; i < 4; ++i) a[i] = *(const float4*)(Xs + (r0 + i) * 128 + cox);
#pragma unroll
        for (int j = 0; j < 4; ++j) b[j] = *(const float4*)(Ws + (c0 + j) * 128 + cow);
#pragma unroll
        for (int i = 0; i < 4; ++i)
#pragma unroll
            for (int j = 0; j < 4; ++j) {
                acc[i][j] = fmaf(a[i].x, b[j].x, acc[i][j]);
                acc[i][j] = fmaf(a[i].y, b[j].y, acc[i][j]);
                acc[i][j] = fmaf(a[i].z, b[j].z, acc[i][j]);
                acc[i][j] = fmaf(a[i].w, b[j].w, acc[i][j]);
            }
    }

    if (c0 < OUT_DIM) {
        float4 bv = *(const float4*)(bias + c0);
#pragma unroll
        for (int i = 0; i < 4; ++i) {
            int gr = rowBase + r0 + i;
            if (gr >= M) continue;
            float4 v = make_float4(acc[i][0] + bv.x, acc[i][1] + bv.y,
                                   acc[i][2] + bv.z, acc[i][3] + bv.w);
            *(float4*)(C + (size_t)gr * OUT_DIM + c0) = v;
        }
    }
}

extern "C" void kernel_launch(void* const* d_in, const int* in_sizes, int n_in,
                              void* d_out, int out_size, void* d_ws, size_t ws_size,
                              hipStream_t stream) {
    const float* x_in   = (const float*)d_in[0];
    const int*   ei     = (const int*)  d_in[1];   // (2,E) int32: src=ei, dst=ei+E
    const float* ew     = (const float*)d_in[2];
    const float* W_emb  = (const float*)d_in[3];
    const float* b_emb  = (const float*)d_in[4];
    const float* W_lin  = (const float*)d_in[5];
    const float* W_anti = (const float*)d_in[6];
    const float* b_conv = (const float*)d_in[7];
    const float* W_out  = (const float*)d_in[8];
    const float* b_out  = (const float*)d_in[9];
    float* out = (float*)d_out;

    // workspace: xF(f32) | xhA | xhB (bf16) | WembH | Wcat2H |
    //            rowStart | cursor | es2(int2) | blockSums    (~57 MB)
    float*  xF     = (float*)d_ws;
    ushort* xhA    = (ushort*)(xF + (size_t)N_NODES * D_DIM);
    ushort* xhB    = xhA + (size_t)N_NODES * D_DIM;
    ushort* WembH  = xhB + (size_t)N_NODES * D_DIM;
    ushort* Wcat2H = WembH + D_DIM * D_DIM;
    int*    rowStart = (int*)(Wcat2H + 2 * D_DIM * D_DIM);
    int*    cursor   = rowStart + N_NODES;
    int2*   es2      = (int2*)(cursor + N_NODES);
    int*    blockSums = (int*)(es2 + E_EDGES);

    const int* src = ei;
    const int* dst = ei + E_EDGES;
    const int edgeBlocks = (E_EDGES + 255) / 256;
    const int gemmBlocksX = (N_NODES + 127) / 128;       // 391

    // ---- CSR build (once; structure is iteration-invariant) ----
    zero_int_kernel<<<SCAN_BLOCKS, 256, 0, stream>>>(cursor, N_NODES);
    hist_kernel<<<edgeBlocks, 256, 0, stream>>>(dst, cursor);
    scan_phase1<<<SCAN_BLOCKS, 256, 0, stream>>>(cursor, rowStart, blockSums);
    scan_phase2<<<1, 256, 0, stream>>>(blockSums);
    scan_phase3<<<SCAN_BLOCKS, 256, 0, stream>>>(rowStart, blockSums, cursor);
    build_kernel<<<edgeBlocks, 256, 0, stream>>>(src, dst, ew, cursor, es2);
    // after build: cursor[d] == row end offset

    // ---- weights to bf16 ----
    prep_w_kernel<<<64, 256, 0, stream>>>(W_emb, W_lin, W_anti, WembH, Wcat2H);

    // ---- embed ----
    mfma_embed_gemm<<<gemmBlocksX, 256, 0, stream>>>(x_in, WembH, b_emb, xF, xhA, N_NODES);

    // ---- iterations (fused gather + conv + update; xh ping-pong) ----
    for (int it = 0; it < N_ITERS; ++it) {
        ushort* xin  = (it & 1) ? xhB : xhA;
        ushort* xout = (it & 1) ? xhA : xhB;
        mfma_conv_gather_update<<<gemmBlocksX, 256, 0, stream>>>(
            xin, es2, rowStart, cursor, Wcat2H, b_conv, xF, xout, N_NODES);
    }
    out_gemm<<<(N_NODES + 63) / 64, 256, 0, stream>>>(xF, W_out, b_out, out, N_NODES);
}

// Round 7
// 514.492 us; speedup vs baseline: 1.0914x; 1.0914x over previous
//
#include <hip/hip_runtime.h>
#include <math.h>

#define N_NODES 50000
#define E_EDGES 600000
#define D_DIM 128
#define OUT_DIM 40
#define N_ITERS 5
#define GAMMA_C 0.1f
#define EPS_C 0.1f
#define SCAN_BLOCKS 196          // 196*256 = 50176 >= N_NODES

typedef short v8s __attribute__((ext_vector_type(8)));   // 8 bf16 (4 VGPRs)
typedef float v4f __attribute__((ext_vector_type(4)));   // MFMA accumulator
typedef unsigned int uint;
typedef unsigned short ushort;

__device__ __forceinline__ ushort f2bf(float f) {        // RNE fp32->bf16
    union { float f; uint u; } v; v.f = f;
    uint u = v.u;
    uint r = 0x7fffu + ((u >> 16) & 1u);
    return (ushort)((u + r) >> 16);
}
__device__ __forceinline__ float bf2f(ushort h) {
    union { uint u; float f; } v; v.u = ((uint)h) << 16;
    return v.f;
}
// pack 8 consecutive fp32 -> v8s (bf16)
__device__ __forceinline__ v8s pack8(const float* __restrict__ p) {
    float4 f0 = *(const float4*)p;
    float4 f1 = *(const float4*)(p + 4);
    v8s r;
    r[0] = (short)f2bf(f0.x); r[1] = (short)f2bf(f0.y);
    r[2] = (short)f2bf(f0.z); r[3] = (short)f2bf(f0.w);
    r[4] = (short)f2bf(f1.x); r[5] = (short)f2bf(f1.y);
    r[6] = (short)f2bf(f1.z); r[7] = (short)f2bf(f1.w);
    return r;
}

// ---------------------------------------------------------------------------
// Weight prep (once): WembH = bf16(W_emb);
// Wcat2[c][k] (row-stride 256): k<128 -> A[c][k]=Wanti[c][k]-Wanti[k][c]-g*I,
//                               k>=128 -> W_lin[c][k-128]
// WoutH: 48x128 bf16 (rows 40..47 zero-padded)
// ---------------------------------------------------------------------------
__global__ __launch_bounds__(256) void prep_w_kernel(const float* __restrict__ Wemb,
                                                     const float* __restrict__ Wlin,
                                                     const float* __restrict__ Wanti,
                                                     const float* __restrict__ Wout,
                                                     ushort* __restrict__ WembH,
                                                     ushort* __restrict__ Wcat2H,
                                                     ushort* __restrict__ WoutH) {
    int i = blockIdx.x * 256 + threadIdx.x;              // 16384
    int r = i >> 7, c = i & 127;
    WembH[i] = f2bf(Wemb[i]);
    float a = Wanti[r * 128 + c] - Wanti[c * 128 + r];
    if (r == c) a -= GAMMA_C;
    Wcat2H[r * 256 + c]       = f2bf(a);
    Wcat2H[r * 256 + 128 + c] = f2bf(Wlin[r * 128 + c]);
    if (i < 48 * 128) WoutH[i] = (r < OUT_DIM) ? f2bf(Wout[r * 128 + c]) : (ushort)0;
}

// ---------------------------------------------------------------------------
// embed GEMM (no LDS): x = x0 @ W_emb^T + b_emb; writes fp32 xF AND bf16 xh.
// Per wave: 64 rows x 64 cols (4x4 16x16x32 frags), A/B read directly from
// global (16B/lane; W L2-resident, X single-use). Fragments per m89/m120:
// A[m=lane&15][k=quad*8+j], B[n=lane&15][k=quad*8+j], C/D col=lane&15,
// row=quad*4+reg.
// ---------------------------------------------------------------------------
__global__ __launch_bounds__(256) void mfma_embed_gemm(const float* __restrict__ Xf,
                                                       const ushort* __restrict__ Wh,
                                                       const float* __restrict__ bias,
                                                       float* __restrict__ xF,
                                                       ushort* __restrict__ xH,
                                                       int M) {
    const int tid = threadIdx.x;
    const int rowBase = blockIdx.x * 128;
    const int lane = tid & 63;
    const int wv = tid >> 6;
    const int wrow = (wv & 1) * 64;
    const int wcol = (wv >> 1) * 64;
    const int l16 = lane & 15;
    const int q = lane >> 4;

    int rowIdx[4];
#pragma unroll
    for (int i = 0; i < 4; ++i) {
        int gr = rowBase + wrow + i * 16 + l16;
        rowIdx[i] = gr < M ? gr : M - 1;       // clamp for loads; store guarded
    }

    v4f acc[4][4];
#pragma unroll
    for (int i = 0; i < 4; ++i)
#pragma unroll
        for (int j = 0; j < 4; ++j) { v4f z = {0.f,0.f,0.f,0.f}; acc[i][j] = z; }

#pragma unroll
    for (int ks = 0; ks < 4; ++ks) {
        const int kb = ks * 32 + q * 8;
        v8s a[4], b[4];
#pragma unroll
        for (int i = 0; i < 4; ++i)
            a[i] = pack8(Xf + (size_t)rowIdx[i] * 128 + kb);
#pragma unroll
        for (int j = 0; j < 4; ++j)
            b[j] = *(const v8s*)(Wh + (size_t)(wcol + j * 16 + l16) * 128 + kb);
#pragma unroll
        for (int i = 0; i < 4; ++i)
#pragma unroll
            for (int j = 0; j < 4; ++j)
                acc[i][j] = __builtin_amdgcn_mfma_f32_16x16x32_bf16(a[i], b[j], acc[i][j], 0, 0, 0);
    }

#pragma unroll
    for (int j = 0; j < 4; ++j) {
        int col = wcol + j * 16 + l16;
        float bj = bias[col];
#pragma unroll
        for (int i = 0; i < 4; ++i) {
            int grB = rowBase + wrow + i * 16 + q * 4;
#pragma unroll
            for (int r = 0; r < 4; ++r) {
                int gr = grB + r;
                if (gr < M) {
                    float v = acc[i][j][r] + bj;
                    xF[(size_t)gr * 128 + col] = v;
                    xH[(size_t)gr * 128 + col] = f2bf(v);
                }
            }
        }
    }
}

// ---------------------------------------------------------------------------
// conv GEMM + update (no LDS): conv = [xh | aggxh] @ Wcat2^T + b_conv (K=256)
//   x += eps*tanh(conv); xh = bf16(x)   (in-place: block owns its rows)
// ---------------------------------------------------------------------------
__global__ __launch_bounds__(256) void mfma_conv_update(
        const ushort* __restrict__ xh, const ushort* __restrict__ aggxh,
        const ushort* __restrict__ Wcat2, const float* __restrict__ bconv,
        float* __restrict__ xF, ushort* __restrict__ xhOut, int M) {
    const int tid = threadIdx.x;
    const int rowBase = blockIdx.x * 128;
    const int lane = tid & 63;
    const int wv = tid >> 6;
    const int wrow = (wv & 1) * 64;
    const int wcol = (wv >> 1) * 64;
    const int l16 = lane & 15;
    const int q = lane >> 4;

    int rowIdx[4];
#pragma unroll
    for (int i = 0; i < 4; ++i) {
        int gr = rowBase + wrow + i * 16 + l16;
        rowIdx[i] = gr < M ? gr : M - 1;
    }

    v4f acc[4][4];
#pragma unroll
    for (int i = 0; i < 4; ++i)
#pragma unroll
        for (int j = 0; j < 4; ++j) { v4f z = {0.f,0.f,0.f,0.f}; acc[i][j] = z; }

#pragma unroll
    for (int kc = 0; kc < 2; ++kc) {
        const ushort* Xsrc = kc ? aggxh : xh;
#pragma unroll
        for (int ks = 0; ks < 4; ++ks) {
            const int kb = ks * 32 + q * 8;
            v8s a[4], b[4];
#pragma unroll
            for (int i = 0; i < 4; ++i)
                a[i] = *(const v8s*)(Xsrc + (size_t)rowIdx[i] * 128 + kb);
#pragma unroll
            for (int j = 0; j < 4; ++j)
                b[j] = *(const v8s*)(Wcat2 + (size_t)(wcol + j * 16 + l16) * 256 + kc * 128 + kb);
#pragma unroll
            for (int i = 0; i < 4; ++i)
#pragma unroll
                for (int j = 0; j < 4; ++j)
                    acc[i][j] = __builtin_amdgcn_mfma_f32_16x16x32_bf16(a[i], b[j], acc[i][j], 0, 0, 0);
        }
    }

#pragma unroll
    for (int j = 0; j < 4; ++j) {
        int col = wcol + j * 16 + l16;
        float bj = bconv[col];
#pragma unroll
        for (int i = 0; i < 4; ++i) {
            int grB = rowBase + wrow + i * 16 + q * 4;
#pragma unroll
            for (int r = 0; r < 4; ++r) {
                int gr = grB + r;
                if (gr < M) {
                    size_t off = (size_t)gr * 128 + col;
                    float conv = acc[i][j][r] + bj;
                    float xv = xF[off] + EPS_C * tanhf(conv);
                    xF[off] = xv;
                    xhOut[off] = f2bf(xv);
                }
            }
        }
    }
}

// ---------------------------------------------------------------------------
// CSR build (once per launch; edge structure is iteration-invariant)
// ---------------------------------------------------------------------------
__global__ __launch_bounds__(256) void zero_int_kernel(int* __restrict__ p, int n) {
    int i = blockIdx.x * 256 + threadIdx.x;
    if (i < n) p[i] = 0;
}

__global__ __launch_bounds__(256) void hist_kernel(const int* __restrict__ dst,
                                                   int* __restrict__ cnt) {
    int e = blockIdx.x * 256 + threadIdx.x;
    if (e < E_EDGES) atomicAdd(&cnt[dst[e]], 1);
}

__global__ __launch_bounds__(256) void scan_phase1(const int* __restrict__ deg,
                                                   int* __restrict__ localEx,
                                                   int* __restrict__ blockSums) {
    __shared__ int tmp[256];
    const int t = threadIdx.x;
    const int i = blockIdx.x * 256 + t;
    int v = (i < N_NODES) ? deg[i] : 0;
    tmp[t] = v;
    __syncthreads();
#pragma unroll
    for (int off = 1; off < 256; off <<= 1) {
        int u = (t >= off) ? tmp[t - off] : 0;
        __syncthreads();
        tmp[t] += u;
        __syncthreads();
    }
    if (i < N_NODES) localEx[i] = tmp[t] - v;
    if (t == 255) blockSums[blockIdx.x] = tmp[255];
}

__global__ __launch_bounds__(256) void scan_phase2(int* __restrict__ blockSums) {
    __shared__ int tmp[256];
    const int t = threadIdx.x;
    int v = (t < SCAN_BLOCKS) ? blockSums[t] : 0;
    tmp[t] = v;
    __syncthreads();
#pragma unroll
    for (int off = 1; off < 256; off <<= 1) {
        int u = (t >= off) ? tmp[t - off] : 0;
        __syncthreads();
        tmp[t] += u;
        __syncthreads();
    }
    if (t < SCAN_BLOCKS) blockSums[t] = tmp[t] - v;
}

__global__ __launch_bounds__(256) void scan_phase3(int* __restrict__ rowStart,
                                                   const int* __restrict__ blockSums,
                                                   int* __restrict__ cursor) {
    const int i = blockIdx.x * 256 + threadIdx.x;
    if (i >= N_NODES) return;
    int v = rowStart[i] + blockSums[blockIdx.x];
    rowStart[i] = v;
    cursor[i] = v;
}

// scatter edges into CSR order, packed {src, bits(w)}: one 8B store/edge
__global__ __launch_bounds__(256) void build_kernel(const int* __restrict__ src,
                                                    const int* __restrict__ dst,
                                                    const float* __restrict__ ew,
                                                    int* __restrict__ cursor,
                                                    int2* __restrict__ es2) {
    int e = blockIdx.x * 256 + threadIdx.x;
    if (e >= E_EDGES) return;
    int d = dst[e];
    int pos = atomicAdd(&cursor[d], 1);
    es2[pos] = make_int2(src[e], __float_as_int(ew[e]));
}

// ---------------------------------------------------------------------------
// Gather raw x: aggxh[n] = bf16( sum_e w_e * xh[src_e] )
// 32 lanes/node, 8B/lane, unroll-4 for memory-level parallelism.
// ---------------------------------------------------------------------------
__global__ __launch_bounds__(256) void gather_x_kernel(
        const ushort* __restrict__ xh, const int2* __restrict__ es2,
        const int* __restrict__ rowStart, const int* __restrict__ rowEnd,
        ushort* __restrict__ aggxh) {
    int gid = blockIdx.x * 256 + threadIdx.x;
    int node = gid >> 5;
    if (node >= N_NODES) return;
    int q = gid & 31;
    int e = rowStart[node], end = rowEnd[node];

    float4 s0 = make_float4(0.f, 0.f, 0.f, 0.f);
    float4 s1 = make_float4(0.f, 0.f, 0.f, 0.f);
    float4 s2 = make_float4(0.f, 0.f, 0.f, 0.f);
    float4 s3 = make_float4(0.f, 0.f, 0.f, 0.f);
    for (; e + 4 <= end; e += 4) {
        int2 m0 = es2[e], m1 = es2[e + 1], m2 = es2[e + 2], m3 = es2[e + 3];
        ushort4 v0 = *(const ushort4*)(xh + (size_t)m0.x * 128 + q * 4);
        ushort4 v1 = *(const ushort4*)(xh + (size_t)m1.x * 128 + q * 4);
        ushort4 v2 = *(const ushort4*)(xh + (size_t)m2.x * 128 + q * 4);
        ushort4 v3 = *(const ushort4*)(xh + (size_t)m3.x * 128 + q * 4);
        float w0 = __int_as_float(m0.y), w1 = __int_as_float(m1.y);
        float w2 = __int_as_float(m2.y), w3 = __int_as_float(m3.y);
        s0.x = fmaf(w0, bf2f(v0.x), s0.x); s0.y = fmaf(w0, bf2f(v0.y), s0.y);
        s0.z = fmaf(w0, bf2f(v0.z), s0.z); s0.w = fmaf(w0, bf2f(v0.w), s0.w);
        s1.x = fmaf(w1, bf2f(v1.x), s1.x); s1.y = fmaf(w1, bf2f(v1.y), s1.y);
        s1.z = fmaf(w1, bf2f(v1.z), s1.z); s1.w = fmaf(w1, bf2f(v1.w), s1.w);
        s2.x = fmaf(w2, bf2f(v2.x), s2.x); s2.y = fmaf(w2, bf2f(v2.y), s2.y);
        s2.z = fmaf(w2, bf2f(v2.z), s2.z); s2.w = fmaf(w2, bf2f(v2.w), s2.w);
        s3.x = fmaf(w3, bf2f(v3.x), s3.x); s3.y = fmaf(w3, bf2f(v3.y), s3.y);
        s3.z = fmaf(w3, bf2f(v3.z), s3.z); s3.w = fmaf(w3, bf2f(v3.w), s3.w);
    }
    for (; e < end; ++e) {
        int2 m = es2[e];
        float w = __int_as_float(m.y);
        ushort4 v = *(const ushort4*)(xh + (size_t)m.x * 128 + q * 4);
        s0.x = fmaf(w, bf2f(v.x), s0.x); s0.y = fmaf(w, bf2f(v.y), s0.y);
        s0.z = fmaf(w, bf2f(v.z), s0.z); s0.w = fmaf(w, bf2f(v.w), s0.w);
    }
    float4 sum = make_float4(s0.x + s1.x + s2.x + s3.x,
                             s0.y + s1.y + s2.y + s3.y,
                             s0.z + s1.z + s2.z + s3.z,
                             s0.w + s1.w + s2.w + s3.w);
    ushort4 h;
    h.x = f2bf(sum.x); h.y = f2bf(sum.y); h.z = f2bf(sum.z); h.w = f2bf(sum.w);
    *(ushort4*)(aggxh + (size_t)node * 128 + q * 4) = h;
}

// ---------------------------------------------------------------------------
// Readout (bf16 MFMA, no LDS): out = xh @ WoutH^T + b_out
// Block = 4 waves x 64 rows = 256 rows; 48 padded cols (40 real).
// ---------------------------------------------------------------------------
__global__ __launch_bounds__(256) void out_gemm_bf16(const ushort* __restrict__ xh,
                                                     const ushort* __restrict__ WoutH,
                                                     const float* __restrict__ bout,
                                                     float* __restrict__ out, int M) {
    const int tid = threadIdx.x;
    const int lane = tid & 63;
    const int wv = tid >> 6;
    const int rowBase = blockIdx.x * 256 + wv * 64;
    const int l16 = lane & 15;
    const int q = lane >> 4;

    int rowIdx[4];
#pragma unroll
    for (int i = 0; i < 4; ++i) {
        int gr = rowBase + i * 16 + l16;
        rowIdx[i] = gr < M ? gr : M - 1;
    }

    v4f acc[4][3];
#pragma unroll
    for (int i = 0; i < 4; ++i)
#pragma unroll
        for (int j = 0; j < 3; ++j) { v4f z = {0.f,0.f,0.f,0.f}; acc[i][j] = z; }

#pragma unroll
    for (int ks = 0; ks < 4; ++ks) {
        const int kb = ks * 32 + q * 8;
        v8s a[4], b[3];
#pragma unroll
        for (int i = 0; i < 4; ++i)
            a[i] = *(const v8s*)(xh + (size_t)rowIdx[i] * 128 + kb);
#pragma unroll
        for (int j = 0; j < 3; ++j)
            b[j] = *(const v8s*)(WoutH + (size_t)(j * 16 + l16) * 128 + kb);
#pragma unroll
        for (int i = 0; i < 4; ++i)
#pragma unroll
            for (int j = 0; j < 3; ++j)
                acc[i][j] = __builtin_amdgcn_mfma_f32_16x16x32_bf16(a[i], b[j], acc[i][j], 0, 0, 0);
    }

#pragma unroll
    for (int j = 0; j < 3; ++j) {
        int col = j * 16 + l16;
        if (col >= OUT_DIM) continue;
        float bj = bout[col];
#pragma unroll
        for (int i = 0; i < 4; ++i) {
            int grB = rowBase + i * 16 + q * 4;
#pragma unroll
            for (int r = 0; r < 4; ++r) {
                int gr = grB + r;
                if (gr < M) out[(size_t)gr * OUT_DIM + col] = acc[i][j][r] + bj;
            }
        }
    }
}

extern "C" void kernel_launch(void* const* d_in, const int* in_sizes, int n_in,
                              void* d_out, int out_size, void* d_ws, size_t ws_size,
                              hipStream_t stream) {
    const float* x_in   = (const float*)d_in[0];
    const int*   ei     = (const int*)  d_in[1];   // (2,E) int32: src=ei, dst=ei+E
    const float* ew     = (const float*)d_in[2];
    const float* W_emb  = (const float*)d_in[3];
    const float* b_emb  = (const float*)d_in[4];
    const float* W_lin  = (const float*)d_in[5];
    const float* W_anti = (const float*)d_in[6];
    const float* b_conv = (const float*)d_in[7];
    const float* W_out  = (const float*)d_in[8];
    const float* b_out  = (const float*)d_in[9];
    float* out = (float*)d_out;

    // workspace: xF(f32) | xh(bf16) | aggxh(bf16) | WembH | Wcat2H | WoutH |
    //            rowStart | cursor | es2(int2) | blockSums    (~57 MB)
    float*  xF     = (float*)d_ws;
    ushort* xh     = (ushort*)(xF + (size_t)N_NODES * D_DIM);
    ushort* aggxh  = xh + (size_t)N_NODES * D_DIM;
    ushort* WembH  = aggxh + (size_t)N_NODES * D_DIM;
    ushort* Wcat2H = WembH + D_DIM * D_DIM;
    ushort* WoutH  = Wcat2H + 2 * D_DIM * D_DIM;
    int*    rowStart = (int*)(WoutH + 48 * D_DIM);
    int*    cursor   = rowStart + N_NODES;
    int2*   es2      = (int2*)(cursor + N_NODES);
    int*    blockSums = (int*)(es2 + E_EDGES);

    const int* src = ei;
    const int* dst = ei + E_EDGES;
    const int edgeBlocks = (E_EDGES + 255) / 256;
    const int gemmBlocksX = (N_NODES + 127) / 128;       // 391

    // ---- CSR build (once; structure is iteration-invariant) ----
    zero_int_kernel<<<SCAN_BLOCKS, 256, 0, stream>>>(cursor, N_NODES);
    hist_kernel<<<edgeBlocks, 256, 0, stream>>>(dst, cursor);
    scan_phase1<<<SCAN_BLOCKS, 256, 0, stream>>>(cursor, rowStart, blockSums);
    scan_phase2<<<1, 256, 0, stream>>>(blockSums);
    scan_phase3<<<SCAN_BLOCKS, 256, 0, stream>>>(rowStart, blockSums, cursor);
    build_kernel<<<edgeBlocks, 256, 0, stream>>>(src, dst, ew, cursor, es2);
    // after build: cursor[d] == row end offset

    // ---- weights to bf16 ----
    prep_w_kernel<<<64, 256, 0, stream>>>(W_emb, W_lin, W_anti, W_out,
                                          WembH, Wcat2H, WoutH);

    // ---- embed ----
    mfma_embed_gemm<<<gemmBlocksX, 256, 0, stream>>>(x_in, WembH, b_emb, xF, xh, N_NODES);

    // ---- iterations: gather (high-occupancy) + conv GEMM (no-LDS MFMA) ----
    for (int it = 0; it < N_ITERS; ++it) {
        gather_x_kernel<<<(N_NODES * 32 + 255) / 256, 256, 0, stream>>>(
            xh, es2, rowStart, cursor, aggxh);
        mfma_conv_update<<<gemmBlocksX, 256, 0, stream>>>(
            xh, aggxh, Wcat2H, b_conv, xF, xh, N_NODES);
    }
    // ---- readout from final xh (bf16 MFMA) ----
    out_gemm_bf16<<<(N_NODES + 255) / 256, 256, 0, stream>>>(xh, WoutH, b_out, out, N_NODES);
}

// Round 8
// 485.353 us; speedup vs baseline: 1.1569x; 1.0600x over previous
//
#include <hip/hip_runtime.h>
#include <math.h>

#define N_NODES 50000
#define E_EDGES 600000
#define D_DIM 128
#define OUT_DIM 40
#define N_ITERS 5
#define GAMMA_C 0.1f
#define EPS_C 0.1f
#define SCAN_BLOCKS 196          // 196*256 = 50176 >= N_NODES

typedef short v8s __attribute__((ext_vector_type(8)));   // 8 bf16 (4 VGPRs)
typedef float v4f __attribute__((ext_vector_type(4)));   // MFMA accumulator
typedef unsigned int uint;
typedef unsigned short ushort;

__device__ __forceinline__ ushort f2bf(float f) {        // RNE fp32->bf16
    union { float f; uint u; } v; v.f = f;
    uint u = v.u;
    uint r = 0x7fffu + ((u >> 16) & 1u);
    return (ushort)((u + r) >> 16);
}
__device__ __forceinline__ float bflo(uint u) {          // low bf16 of packed pair
    union { uint u; float f; } v; v.u = u << 16; return v.f;
}
__device__ __forceinline__ float bfhi(uint u) {          // high bf16 of packed pair
    union { uint u; float f; } v; v.u = u & 0xffff0000u; return v.f;
}

// ---------------------------------------------------------------------------
// Combined (once): zero cursor[N]  +  weight prep to bf16.
// Wcat2[c][k] (row-stride 256): k<128 -> A[c][k]=Wanti[c][k]-Wanti[k][c]-g*I,
//                               k>=128 -> W_lin[c][k-128]
// WoutH: 48x128 bf16 (rows 40..47 zero-padded)
// ---------------------------------------------------------------------------
__global__ __launch_bounds__(256) void zero_prep_kernel(int* __restrict__ cursor,
                                                        const float* __restrict__ Wemb,
                                                        const float* __restrict__ Wlin,
                                                        const float* __restrict__ Wanti,
                                                        const float* __restrict__ Wout,
                                                        ushort* __restrict__ WembH,
                                                        ushort* __restrict__ Wcat2H,
                                                        ushort* __restrict__ WoutH) {
    int i = blockIdx.x * 256 + threadIdx.x;
    if (i < N_NODES) cursor[i] = 0;
    if (i < D_DIM * D_DIM) {
        int r = i >> 7, c = i & 127;
        WembH[i] = f2bf(Wemb[i]);
        float a = Wanti[r * 128 + c] - Wanti[c * 128 + r];
        if (r == c) a -= GAMMA_C;
        Wcat2H[r * 256 + c]       = f2bf(a);
        Wcat2H[r * 256 + 128 + c] = f2bf(Wlin[r * 128 + c]);
        if (i < 48 * 128) WoutH[i] = (r < OUT_DIM) ? f2bf(Wout[r * 128 + c]) : (ushort)0;
    }
}

// ---------------------------------------------------------------------------
// embed GEMM (hybrid): x = x0 @ W_emb^T + b_emb; fp32 X staged->bf16 LDS
// (coalesced A), W read from global (L2-hot). 128x128 tile, 4 waves.
// Fragments (verified m89/m120): A[m=lane&15][k=quad*8+j],
// B[n=lane&15][k=quad*8+j], C/D: col=lane&15, row=quad*4+reg.
// ---------------------------------------------------------------------------
__global__ __launch_bounds__(256) void mfma_embed_gemm(const float* __restrict__ Xf,
                                                       const ushort* __restrict__ Wh,
                                                       const float* __restrict__ bias,
                                                       float* __restrict__ xF,
                                                       ushort* __restrict__ xH,
                                                       int M) {
    __shared__ ushort Xs[128 * 128];          // 32 KB
    const int tid = threadIdx.x;
    const int rowBase = blockIdx.x * 128;

#pragma unroll
    for (int p = 0; p < 8; ++p) {
        int cid = p * 256 + tid;
        int r = cid >> 4, c8 = cid & 15;
        int gr = rowBase + r;
        uint4 val = make_uint4(0, 0, 0, 0);
        if (gr < M) {
            const float* ptr = Xf + (size_t)gr * 128 + c8 * 8;
            float4 f0 = *(const float4*)ptr;
            float4 f1 = *(const float4*)(ptr + 4);
            val.x = (uint)f2bf(f0.x) | ((uint)f2bf(f0.y) << 16);
            val.y = (uint)f2bf(f0.z) | ((uint)f2bf(f0.w) << 16);
            val.z = (uint)f2bf(f1.x) | ((uint)f2bf(f1.y) << 16);
            val.w = (uint)f2bf(f1.z) | ((uint)f2bf(f1.w) << 16);
        }
        *(uint4*)(Xs + r * 128 + ((c8 ^ (r & 7)) << 3)) = val;
    }
    __syncthreads();

    const int lane = tid & 63;
    const int wv = tid >> 6;
    const int wrow = (wv & 1) * 64;
    const int wcol = (wv >> 1) * 64;
    const int l16 = lane & 15;
    const int q = lane >> 4;

    v4f acc[4][4];
#pragma unroll
    for (int i = 0; i < 4; ++i)
#pragma unroll
        for (int j = 0; j < 4; ++j) { v4f z = {0.f,0.f,0.f,0.f}; acc[i][j] = z; }

#pragma unroll
    for (int ks = 0; ks < 4; ++ks) {
        const int chunk = ks * 4 + q;
        v8s a[4], b[4];
#pragma unroll
        for (int i = 0; i < 4; ++i) {
            int m = wrow + i * 16 + l16;
            a[i] = *(const v8s*)(Xs + m * 128 + ((chunk ^ (m & 7)) << 3));
        }
#pragma unroll
        for (int j = 0; j < 4; ++j)
            b[j] = *(const v8s*)(Wh + (size_t)(wcol + j * 16 + l16) * 128 + chunk * 8);
#pragma unroll
        for (int i = 0; i < 4; ++i)
#pragma unroll
            for (int j = 0; j < 4; ++j)
                acc[i][j] = __builtin_amdgcn_mfma_f32_16x16x32_bf16(a[i], b[j], acc[i][j], 0, 0, 0);
    }

#pragma unroll
    for (int j = 0; j < 4; ++j) {
        int col = wcol + j * 16 + l16;
        float bj = bias[col];
#pragma unroll
        for (int i = 0; i < 4; ++i) {
            int grB = rowBase + wrow + i * 16 + q * 4;
#pragma unroll
            for (int r = 0; r < 4; ++r) {
                int gr = grB + r;
                if (gr < M) {
                    float v = acc[i][j][r] + bj;
                    xF[(size_t)gr * 128 + col] = v;
                    xH[(size_t)gr * 128 + col] = f2bf(v);
                }
            }
        }
    }
}

// ---------------------------------------------------------------------------
// conv GEMM + update (hybrid LDS): conv = [xh | aggxh] @ Wcat2^T + b_conv
// (K=256 as two staged K=128 chunks in ONE 32 KB LDS buffer), then
//   x += eps*tanh(conv); xh = bf16(x)   (in-place: block owns its rows)
// ---------------------------------------------------------------------------
__global__ __launch_bounds__(256) void mfma_conv_update(
        const ushort* __restrict__ xh, const ushort* __restrict__ aggxh,
        const ushort* __restrict__ Wcat2, const float* __restrict__ bconv,
        float* __restrict__ xF, ushort* __restrict__ xhOut, int M) {
    __shared__ ushort Xs[128 * 128];          // 32 KB, reused per chunk
    const int tid = threadIdx.x;
    const int rowBase = blockIdx.x * 128;
    const int lane = tid & 63;
    const int wv = tid >> 6;
    const int wrow = (wv & 1) * 64;
    const int wcol = (wv >> 1) * 64;
    const int l16 = lane & 15;
    const int q = lane >> 4;

    v4f acc[4][4];
#pragma unroll
    for (int i = 0; i < 4; ++i)
#pragma unroll
        for (int j = 0; j < 4; ++j) { v4f z = {0.f,0.f,0.f,0.f}; acc[i][j] = z; }

#pragma unroll
    for (int kc = 0; kc < 2; ++kc) {
        const ushort* Xsrc = kc ? aggxh : xh;
        if (kc) __syncthreads();              // all reads of chunk0 done
#pragma unroll
        for (int p = 0; p < 8; ++p) {
            int cid = p * 256 + tid;
            int r = cid >> 4, c8 = cid & 15;
            int gr = rowBase + r;
            uint4 xv = make_uint4(0, 0, 0, 0);
            if (gr < M) xv = *(const uint4*)(Xsrc + (size_t)gr * 128 + c8 * 8);
            *(uint4*)(Xs + r * 128 + ((c8 ^ (r & 7)) << 3)) = xv;
        }
        __syncthreads();

#pragma unroll
        for (int ks = 0; ks < 4; ++ks) {
            const int chunk = ks * 4 + q;
            v8s a[4], b[4];
#pragma unroll
            for (int i = 0; i < 4; ++i) {
                int m = wrow + i * 16 + l16;
                a[i] = *(const v8s*)(Xs + m * 128 + ((chunk ^ (m & 7)) << 3));
            }
#pragma unroll
            for (int j = 0; j < 4; ++j)
                b[j] = *(const v8s*)(Wcat2 + (size_t)(wcol + j * 16 + l16) * 256 + kc * 128 + chunk * 8);
#pragma unroll
            for (int i = 0; i < 4; ++i)
#pragma unroll
                for (int j = 0; j < 4; ++j)
                    acc[i][j] = __builtin_amdgcn_mfma_f32_16x16x32_bf16(a[i], b[j], acc[i][j], 0, 0, 0);
        }
    }

#pragma unroll
    for (int j = 0; j < 4; ++j) {
        int col = wcol + j * 16 + l16;
        float bj = bconv[col];
#pragma unroll
        for (int i = 0; i < 4; ++i) {
            int grB = rowBase + wrow + i * 16 + q * 4;
#pragma unroll
            for (int r = 0; r < 4; ++r) {
                int gr = grB + r;
                if (gr < M) {
                    size_t off = (size_t)gr * 128 + col;
                    float conv = acc[i][j][r] + bj;
                    float xv = xF[off] + EPS_C * tanhf(conv);
                    xF[off] = xv;
                    xhOut[off] = f2bf(xv);
                }
            }
        }
    }
}

// ---------------------------------------------------------------------------
// CSR build (once per launch; edge structure is iteration-invariant)
// ---------------------------------------------------------------------------
__global__ __launch_bounds__(256) void hist_kernel(const int* __restrict__ dst,
                                                   int* __restrict__ cnt) {
    int e = blockIdx.x * 256 + threadIdx.x;
    if (e < E_EDGES) atomicAdd(&cnt[dst[e]], 1);
}

__global__ __launch_bounds__(256) void scan_phase1(const int* __restrict__ deg,
                                                   int* __restrict__ localEx,
                                                   int* __restrict__ blockSums) {
    __shared__ int tmp[256];
    const int t = threadIdx.x;
    const int i = blockIdx.x * 256 + t;
    int v = (i < N_NODES) ? deg[i] : 0;
    tmp[t] = v;
    __syncthreads();
#pragma unroll
    for (int off = 1; off < 256; off <<= 1) {
        int u = (t >= off) ? tmp[t - off] : 0;
        __syncthreads();
        tmp[t] += u;
        __syncthreads();
    }
    if (i < N_NODES) localEx[i] = tmp[t] - v;
    if (t == 255) blockSums[blockIdx.x] = tmp[255];
}

__global__ __launch_bounds__(256) void scan_phase2(int* __restrict__ blockSums) {
    __shared__ int tmp[256];
    const int t = threadIdx.x;
    int v = (t < SCAN_BLOCKS) ? blockSums[t] : 0;
    tmp[t] = v;
    __syncthreads();
#pragma unroll
    for (int off = 1; off < 256; off <<= 1) {
        int u = (t >= off) ? tmp[t - off] : 0;
        __syncthreads();
        tmp[t] += u;
        __syncthreads();
    }
    if (t < SCAN_BLOCKS) blockSums[t] = tmp[t] - v;
}

__global__ __launch_bounds__(256) void scan_phase3(int* __restrict__ rowStart,
                                                   const int* __restrict__ blockSums,
                                                   int* __restrict__ cursor) {
    const int i = blockIdx.x * 256 + threadIdx.x;
    if (i >= N_NODES) return;
    int v = rowStart[i] + blockSums[blockIdx.x];
    rowStart[i] = v;
    cursor[i] = v;
}

// scatter edges into CSR order, packed {src, bits(w)}: one 8B store/edge
__global__ __launch_bounds__(256) void build_kernel(const int* __restrict__ src,
                                                    const int* __restrict__ dst,
                                                    const float* __restrict__ ew,
                                                    int* __restrict__ cursor,
                                                    int2* __restrict__ es2) {
    int e = blockIdx.x * 256 + threadIdx.x;
    if (e >= E_EDGES) return;
    int d = dst[e];
    int pos = atomicAdd(&cursor[d], 1);
    es2[pos] = make_int2(src[e], __float_as_int(ew[e]));
}

// ---------------------------------------------------------------------------
// Gather raw x: aggxh[n] = bf16( sum_e w_e * xh[src_e] )
// 16 lanes/node (16 B uint4/lane; 4 nodes/wave), unroll-4 -> 16 independent
// load chains per wave. Per edge: 16 lanes x 16 B = 256 B coalesced row read.
// ---------------------------------------------------------------------------
__global__ __launch_bounds__(256) void gather_x_kernel(
        const ushort* __restrict__ xh, const int2* __restrict__ es2,
        const int* __restrict__ rowStart, const int* __restrict__ rowEnd,
        ushort* __restrict__ aggxh) {
    int gid = blockIdx.x * 256 + threadIdx.x;
    int node = gid >> 4;
    if (node >= N_NODES) return;
    int q = gid & 15;                     // elems [q*8, q*8+8)
    int e = rowStart[node], end = rowEnd[node];

    float sA[8] = {0,0,0,0,0,0,0,0};
    float sB[8] = {0,0,0,0,0,0,0,0};
    for (; e + 4 <= end; e += 4) {
        int2 m0 = es2[e], m1 = es2[e + 1], m2 = es2[e + 2], m3 = es2[e + 3];
        uint4 v0 = *(const uint4*)(xh + (size_t)m0.x * 128 + q * 8);
        uint4 v1 = *(const uint4*)(xh + (size_t)m1.x * 128 + q * 8);
        uint4 v2 = *(const uint4*)(xh + (size_t)m2.x * 128 + q * 8);
        uint4 v3 = *(const uint4*)(xh + (size_t)m3.x * 128 + q * 8);
        float w0 = __int_as_float(m0.y), w1 = __int_as_float(m1.y);
        float w2 = __int_as_float(m2.y), w3 = __int_as_float(m3.y);
        sA[0] = fmaf(w0, bflo(v0.x), sA[0]); sA[1] = fmaf(w0, bfhi(v0.x), sA[1]);
        sA[2] = fmaf(w0, bflo(v0.y), sA[2]); sA[3] = fmaf(w0, bfhi(v0.y), sA[3]);
        sA[4] = fmaf(w0, bflo(v0.z), sA[4]); sA[5] = fmaf(w0, bfhi(v0.z), sA[5]);
        sA[6] = fmaf(w0, bflo(v0.w), sA[6]); sA[7] = fmaf(w0, bfhi(v0.w), sA[7]);
        sB[0] = fmaf(w1, bflo(v1.x), sB[0]); sB[1] = fmaf(w1, bfhi(v1.x), sB[1]);
        sB[2] = fmaf(w1, bflo(v1.y), sB[2]); sB[3] = fmaf(w1, bfhi(v1.y), sB[3]);
        sB[4] = fmaf(w1, bflo(v1.z), sB[4]); sB[5] = fmaf(w1, bfhi(v1.z), sB[5]);
        sB[6] = fmaf(w1, bflo(v1.w), sB[6]); sB[7] = fmaf(w1, bfhi(v1.w), sB[7]);
        sA[0] = fmaf(w2, bflo(v2.x), sA[0]); sA[1] = fmaf(w2, bfhi(v2.x), sA[1]);
        sA[2] = fmaf(w2, bflo(v2.y), sA[2]); sA[3] = fmaf(w2, bfhi(v2.y), sA[3]);
        sA[4] = fmaf(w2, bflo(v2.z), sA[4]); sA[5] = fmaf(w2, bfhi(v2.z), sA[5]);
        sA[6] = fmaf(w2, bflo(v2.w), sA[6]); sA[7] = fmaf(w2, bfhi(v2.w), sA[7]);
        sB[0] = fmaf(w3, bflo(v3.x), sB[0]); sB[1] = fmaf(w3, bfhi(v3.x), sB[1]);
        sB[2] = fmaf(w3, bflo(v3.y), sB[2]); sB[3] = fmaf(w3, bfhi(v3.y), sB[3]);
        sB[4] = fmaf(w3, bflo(v3.z), sB[4]); sB[5] = fmaf(w3, bfhi(v3.z), sB[5]);
        sB[6] = fmaf(w3, bflo(v3.w), sB[6]); sB[7] = fmaf(w3, bfhi(v3.w), sB[7]);
    }
    for (; e < end; ++e) {
        int2 m = es2[e];
        float w = __int_as_float(m.y);
        uint4 v = *(const uint4*)(xh + (size_t)m.x * 128 + q * 8);
        sA[0] = fmaf(w, bflo(v.x), sA[0]); sA[1] = fmaf(w, bfhi(v.x), sA[1]);
        sA[2] = fmaf(w, bflo(v.y), sA[2]); sA[3] = fmaf(w, bfhi(v.y), sA[3]);
        sA[4] = fmaf(w, bflo(v.z), sA[4]); sA[5] = fmaf(w, bfhi(v.z), sA[5]);
        sA[6] = fmaf(w, bflo(v.w), sA[6]); sA[7] = fmaf(w, bfhi(v.w), sA[7]);
    }
    uint4 o;
    o.x = (uint)f2bf(sA[0] + sB[0]) | ((uint)f2bf(sA[1] + sB[1]) << 16);
    o.y = (uint)f2bf(sA[2] + sB[2]) | ((uint)f2bf(sA[3] + sB[3]) << 16);
    o.z = (uint)f2bf(sA[4] + sB[4]) | ((uint)f2bf(sA[5] + sB[5]) << 16);
    o.w = (uint)f2bf(sA[6] + sB[6]) | ((uint)f2bf(sA[7] + sB[7]) << 16);
    *(uint4*)(aggxh + (size_t)node * 128 + q * 8) = o;
}

// ---------------------------------------------------------------------------
// Readout (bf16 MFMA, no LDS): out = xh @ WoutH^T + b_out
// ---------------------------------------------------------------------------
__global__ __launch_bounds__(256) void out_gemm_bf16(const ushort* __restrict__ xh,
                                                     const ushort* __restrict__ WoutH,
                                                     const float* __restrict__ bout,
                                                     float* __restrict__ out, int M) {
    const int tid = threadIdx.x;
    const int lane = tid & 63;
    const int wv = tid >> 6;
    const int rowBase = blockIdx.x * 256 + wv * 64;
    const int l16 = lane & 15;
    const int q = lane >> 4;

    int rowIdx[4];
#pragma unroll
    for (int i = 0; i < 4; ++i) {
        int gr = rowBase + i * 16 + l16;
        rowIdx[i] = gr < M ? gr : M - 1;
    }

    v4f acc[4][3];
#pragma unroll
    for (int i = 0; i < 4; ++i)
#pragma unroll
        for (int j = 0; j < 3; ++j) { v4f z = {0.f,0.f,0.f,0.f}; acc[i][j] = z; }

#pragma unroll
    for (int ks = 0; ks < 4; ++ks) {
        const int kb = ks * 32 + q * 8;
        v8s a[4], b[3];
#pragma unroll
        for (int i = 0; i < 4; ++i)
            a[i] = *(const v8s*)(xh + (size_t)rowIdx[i] * 128 + kb);
#pragma unroll
        for (int j = 0; j < 3; ++j)
            b[j] = *(const v8s*)(WoutH + (size_t)(j * 16 + l16) * 128 + kb);
#pragma unroll
        for (int i = 0; i < 4; ++i)
#pragma unroll
            for (int j = 0; j < 3; ++j)
                acc[i][j] = __builtin_amdgcn_mfma_f32_16x16x32_bf16(a[i], b[j], acc[i][j], 0, 0, 0);
    }

#pragma unroll
    for (int j = 0; j < 3; ++j) {
        int col = j * 16 + l16;
        if (col >= OUT_DIM) continue;
        float bj = bout[col];
#pragma unroll
        for (int i = 0; i < 4; ++i) {
            int grB = rowBase + i * 16 + q * 4;
#pragma unroll
            for (int r = 0; r < 4; ++r) {
                int gr = grB + r;
                if (gr < M) out[(size_t)gr * OUT_DIM + col] = acc[i][j][r] + bj;
            }
        }
    }
}

extern "C" void kernel_launch(void* const* d_in, const int* in_sizes, int n_in,
                              void* d_out, int out_size, void* d_ws, size_t ws_size,
                              hipStream_t stream) {
    const float* x_in   = (const float*)d_in[0];
    const int*   ei     = (const int*)  d_in[1];   // (2,E) int32: src=ei, dst=ei+E
    const float* ew     = (const float*)d_in[2];
    const float* W_emb  = (const float*)d_in[3];
    const float* b_emb  = (const float*)d_in[4];
    const float* W_lin  = (const float*)d_in[5];
    const float* W_anti = (const float*)d_in[6];
    const float* b_conv = (const float*)d_in[7];
    const float* W_out  = (const float*)d_in[8];
    const float* b_out  = (const float*)d_in[9];
    float* out = (float*)d_out;

    // workspace: xF(f32) | xh(bf16) | aggxh(bf16) | WembH | Wcat2H | WoutH |
    //            rowStart | cursor | es2(int2) | blockSums    (~57 MB)
    float*  xF     = (float*)d_ws;
    ushort* xh     = (ushort*)(xF + (size_t)N_NODES * D_DIM);
    ushort* aggxh  = xh + (size_t)N_NODES * D_DIM;
    ushort* WembH  = aggxh + (size_t)N_NODES * D_DIM;
    ushort* Wcat2H = WembH + D_DIM * D_DIM;
    ushort* WoutH  = Wcat2H + 2 * D_DIM * D_DIM;
    int*    rowStart = (int*)(WoutH + 48 * D_DIM);
    int*    cursor   = rowStart + N_NODES;
    int2*   es2      = (int2*)(cursor + N_NODES);
    int*    blockSums = (int*)(es2 + E_EDGES);

    const int* src = ei;
    const int* dst = ei + E_EDGES;
    const int edgeBlocks = (E_EDGES + 255) / 256;
    const int gemmBlocksX = (N_NODES + 127) / 128;       // 391

    // ---- CSR build + weight prep (once; structure is iteration-invariant) ----
    zero_prep_kernel<<<SCAN_BLOCKS, 256, 0, stream>>>(cursor, W_emb, W_lin, W_anti,
                                                      W_out, WembH, Wcat2H, WoutH);
    hist_kernel<<<edgeBlocks, 256, 0, stream>>>(dst, cursor);
    scan_phase1<<<SCAN_BLOCKS, 256, 0, stream>>>(cursor, rowStart, blockSums);
    scan_phase2<<<1, 256, 0, stream>>>(blockSums);
    scan_phase3<<<SCAN_BLOCKS, 256, 0, stream>>>(rowStart, blockSums, cursor);
    build_kernel<<<edgeBlocks, 256, 0, stream>>>(src, dst, ew, cursor, es2);
    // after build: cursor[d] == row end offset

    // ---- embed ----
    mfma_embed_gemm<<<gemmBlocksX, 256, 0, stream>>>(x_in, WembH, b_emb, xF, xh, N_NODES);

    // ---- iterations: gather (high-occupancy) + conv GEMM (hybrid LDS) ----
    for (int it = 0; it < N_ITERS; ++it) {
        gather_x_kernel<<<(N_NODES * 16 + 255) / 256, 256, 0, stream>>>(
            xh, es2, rowStart, cursor, aggxh);
        mfma_conv_update<<<gemmBlocksX, 256, 0, stream>>>(
            xh, aggxh, Wcat2H, b_conv, xF, xh, N_NODES);
    }
    // ---- readout from final xh (bf16 MFMA) ----
    out_gemm_bf16<<<(N_NODES + 255) / 256, 256, 0, stream>>>(xh, WoutH, b_out, out, N_NODES);
}

// Round 9
// 454.669 us; speedup vs baseline: 1.2350x; 1.0675x over previous
//
#include <hip/hip_runtime.h>
#include <math.h>

#define N_NODES 50000
#define E_EDGES 600000
#define D_DIM 128
#define OUT_DIM 40
#define N_ITERS 5
#define GAMMA_C 0.1f
#define EPS_C 0.1f
#define SCAN_BLOCKS 196          // 196*256 = 50176 >= N_NODES

typedef short v8s __attribute__((ext_vector_type(8)));   // 8 bf16 (4 VGPRs)
typedef float v4f __attribute__((ext_vector_type(4)));   // MFMA accumulator
typedef unsigned int uint;
typedef unsigned short ushort;

__device__ __forceinline__ ushort f2bf(float f) {        // RNE fp32->bf16
    union { float f; uint u; } v; v.f = f;
    uint u = v.u;
    uint r = 0x7fffu + ((u >> 16) & 1u);
    return (ushort)((u + r) >> 16);
}
__device__ __forceinline__ float bf2f(ushort h) {
    union { uint u; float f; } v; v.u = ((uint)h) << 16;
    return v.f;
}
__device__ __forceinline__ float bflo(uint u) {
    union { uint u; float f; } v; v.u = u << 16; return v.f;
}
__device__ __forceinline__ float bfhi(uint u) {
    union { uint u; float f; } v; v.u = u & 0xffff0000u; return v.f;
}

// ---------------------------------------------------------------------------
// Combined (once): zero cursor[N] + weight prep to bf16.
// Wcat2[c][k] (row-stride 256): k<128 -> A[c][k]=Wanti[c][k]-Wanti[k][c]-g*I,
//                               k>=128 -> W_lin[c][k-128]
// WoutH: 48x128 bf16 (rows 40..47 zero-padded)
// ---------------------------------------------------------------------------
__global__ __launch_bounds__(256) void zero_prep_kernel(int* __restrict__ cursor,
                                                        const float* __restrict__ Wemb,
                                                        const float* __restrict__ Wlin,
                                                        const float* __restrict__ Wanti,
                                                        const float* __restrict__ Wout,
                                                        ushort* __restrict__ WembH,
                                                        ushort* __restrict__ Wcat2H,
                                                        ushort* __restrict__ WoutH) {
    int i = blockIdx.x * 256 + threadIdx.x;
    if (i < N_NODES) cursor[i] = 0;
    if (i < D_DIM * D_DIM) {
        int r = i >> 7, c = i & 127;
        WembH[i] = f2bf(Wemb[i]);
        float a = Wanti[r * 128 + c] - Wanti[c * 128 + r];
        if (r == c) a -= GAMMA_C;
        Wcat2H[r * 256 + c]       = f2bf(a);
        Wcat2H[r * 256 + 128 + c] = f2bf(Wlin[r * 128 + c]);
        if (i < 48 * 128) WoutH[i] = (r < OUT_DIM) ? f2bf(Wout[r * 128 + c]) : (ushort)0;
    }
}

// ---------------------------------------------------------------------------
// embed GEMM (hybrid): xh = bf16(x0 @ W_emb^T + b_emb). fp32 X staged->bf16
// LDS (coalesced A), W from global (L2-hot). 128x128 tile, 4 waves.
// Fragments (verified m89/m120): A[m=lane&15][k=quad*8+j],
// B[n=lane&15][k=quad*8+j], C/D: col=lane&15, row=quad*4+reg.
// ---------------------------------------------------------------------------
__global__ __launch_bounds__(256) void mfma_embed_gemm(const float* __restrict__ Xf,
                                                       const ushort* __restrict__ Wh,
                                                       const float* __restrict__ bias,
                                                       ushort* __restrict__ xH,
                                                       int M) {
    __shared__ ushort Xs[128 * 128];          // 32 KB
    const int tid = threadIdx.x;
    const int rowBase = blockIdx.x * 128;

#pragma unroll
    for (int p = 0; p < 8; ++p) {
        int cid = p * 256 + tid;
        int r = cid >> 4, c8 = cid & 15;
        int gr = rowBase + r;
        uint4 val = make_uint4(0, 0, 0, 0);
        if (gr < M) {
            const float* ptr = Xf + (size_t)gr * 128 + c8 * 8;
            float4 f0 = *(const float4*)ptr;
            float4 f1 = *(const float4*)(ptr + 4);
            val.x = (uint)f2bf(f0.x) | ((uint)f2bf(f0.y) << 16);
            val.y = (uint)f2bf(f0.z) | ((uint)f2bf(f0.w) << 16);
            val.z = (uint)f2bf(f1.x) | ((uint)f2bf(f1.y) << 16);
            val.w = (uint)f2bf(f1.z) | ((uint)f2bf(f1.w) << 16);
        }
        *(uint4*)(Xs + r * 128 + ((c8 ^ (r & 7)) << 3)) = val;
    }
    __syncthreads();

    const int lane = tid & 63;
    const int wv = tid >> 6;
    const int wrow = (wv & 1) * 64;
    const int wcol = (wv >> 1) * 64;
    const int l16 = lane & 15;
    const int q = lane >> 4;

    v4f acc[4][4];
#pragma unroll
    for (int i = 0; i < 4; ++i)
#pragma unroll
        for (int j = 0; j < 4; ++j) { v4f z = {0.f,0.f,0.f,0.f}; acc[i][j] = z; }

#pragma unroll
    for (int ks = 0; ks < 4; ++ks) {
        const int chunk = ks * 4 + q;
        v8s a[4], b[4];
#pragma unroll
        for (int i = 0; i < 4; ++i) {
            int m = wrow + i * 16 + l16;
            a[i] = *(const v8s*)(Xs + m * 128 + ((chunk ^ (m & 7)) << 3));
        }
#pragma unroll
        for (int j = 0; j < 4; ++j)
            b[j] = *(const v8s*)(Wh + (size_t)(wcol + j * 16 + l16) * 128 + chunk * 8);
#pragma unroll
        for (int i = 0; i < 4; ++i)
#pragma unroll
            for (int j = 0; j < 4; ++j)
                acc[i][j] = __builtin_amdgcn_mfma_f32_16x16x32_bf16(a[i], b[j], acc[i][j], 0, 0, 0);
    }

#pragma unroll
    for (int j = 0; j < 4; ++j) {
        int col = wcol + j * 16 + l16;
        float bj = bias[col];
#pragma unroll
        for (int i = 0; i < 4; ++i) {
            int grB = rowBase + wrow + i * 16 + q * 4;
#pragma unroll
            for (int r = 0; r < 4; ++r) {
                int gr = grB + r;
                if (gr < M) xH[(size_t)gr * 128 + col] = f2bf(acc[i][j][r] + bj);
            }
        }
    }
}

// ---------------------------------------------------------------------------
// conv GEMM + update (bf16 state, hybrid LDS):
//   conv = aggxh@W_lin^T + xh@A^T + b_conv    (two staged K=128 chunks)
//   xh  += bf16( eps*tanh(conv) )             (in-place; block owns its rows)
// Chunk order: aggxh first, xh second — epilogue's xh re-read hits L2.
// ---------------------------------------------------------------------------
__global__ __launch_bounds__(256) void mfma_conv_update(
        ushort* __restrict__ xh, const ushort* __restrict__ aggxh,
        const ushort* __restrict__ Wcat2, const float* __restrict__ bconv,
        int M) {
    __shared__ ushort Xs[128 * 128];          // 32 KB, reused per chunk
    const int tid = threadIdx.x;
    const int rowBase = blockIdx.x * 128;
    const int lane = tid & 63;
    const int wv = tid >> 6;
    const int wrow = (wv & 1) * 64;
    const int wcol = (wv >> 1) * 64;
    const int l16 = lane & 15;
    const int q = lane >> 4;

    v4f acc[4][4];
#pragma unroll
    for (int i = 0; i < 4; ++i)
#pragma unroll
        for (int j = 0; j < 4; ++j) { v4f z = {0.f,0.f,0.f,0.f}; acc[i][j] = z; }

#pragma unroll
    for (int kc = 0; kc < 2; ++kc) {
        // kc=0: A-src = aggxh, W chunk = W_lin (k in [128,256))
        // kc=1: A-src = xh,    W chunk = A     (k in [0,128))
        const ushort* Xsrc = kc ? xh : aggxh;
        const int wOff = kc ? 0 : 128;
        if (kc) __syncthreads();              // all reads of chunk0 done
#pragma unroll
        for (int p = 0; p < 8; ++p) {
            int cid = p * 256 + tid;
            int r = cid >> 4, c8 = cid & 15;
            int gr = rowBase + r;
            uint4 xv = make_uint4(0, 0, 0, 0);
            if (gr < M) xv = *(const uint4*)(Xsrc + (size_t)gr * 128 + c8 * 8);
            *(uint4*)(Xs + r * 128 + ((c8 ^ (r & 7)) << 3)) = xv;
        }
        __syncthreads();

#pragma unroll
        for (int ks = 0; ks < 4; ++ks) {
            const int chunk = ks * 4 + q;
            v8s a[4], b[4];
#pragma unroll
            for (int i = 0; i < 4; ++i) {
                int m = wrow + i * 16 + l16;
                a[i] = *(const v8s*)(Xs + m * 128 + ((chunk ^ (m & 7)) << 3));
            }
#pragma unroll
            for (int j = 0; j < 4; ++j)
                b[j] = *(const v8s*)(Wcat2 + (size_t)(wcol + j * 16 + l16) * 256 + wOff + chunk * 8);
#pragma unroll
            for (int i = 0; i < 4; ++i)
#pragma unroll
                for (int j = 0; j < 4; ++j)
                    acc[i][j] = __builtin_amdgcn_mfma_f32_16x16x32_bf16(a[i], b[j], acc[i][j], 0, 0, 0);
        }
    }

    // epilogue: xh = bf16( xh + eps*tanh(conv) ); xh rows are L2-hot.
#pragma unroll
    for (int j = 0; j < 4; ++j) {
        int col = wcol + j * 16 + l16;
        float bj = bconv[col];
#pragma unroll
        for (int i = 0; i < 4; ++i) {
            int grB = rowBase + wrow + i * 16 + q * 4;
#pragma unroll
            for (int r = 0; r < 4; ++r) {
                int gr = grB + r;
                if (gr < M) {
                    size_t off = (size_t)gr * 128 + col;
                    float conv = acc[i][j][r] + bj;
                    float xv = bf2f(xh[off]) + EPS_C * tanhf(conv);
                    xh[off] = f2bf(xv);
                }
            }
        }
    }
}

// ---------------------------------------------------------------------------
// CSR build (once per launch; edge structure is iteration-invariant)
// ---------------------------------------------------------------------------
__global__ __launch_bounds__(256) void hist_kernel(const int* __restrict__ dst,
                                                   int* __restrict__ cnt) {
    int e = blockIdx.x * 256 + threadIdx.x;
    if (e < E_EDGES) atomicAdd(&cnt[dst[e]], 1);
}

__global__ __launch_bounds__(256) void scan_phase1(const int* __restrict__ deg,
                                                   int* __restrict__ localEx,
                                                   int* __restrict__ blockSums) {
    __shared__ int tmp[256];
    const int t = threadIdx.x;
    const int i = blockIdx.x * 256 + t;
    int v = (i < N_NODES) ? deg[i] : 0;
    tmp[t] = v;
    __syncthreads();
#pragma unroll
    for (int off = 1; off < 256; off <<= 1) {
        int u = (t >= off) ? tmp[t - off] : 0;
        __syncthreads();
        tmp[t] += u;
        __syncthreads();
    }
    if (i < N_NODES) localEx[i] = tmp[t] - v;
    if (t == 255) blockSums[blockIdx.x] = tmp[255];
}

// merged phase2+3: every block redundantly scans the 196 block sums (read-only),
// picks its own exclusive offset, and finalizes rowStart + cursor.
__global__ __launch_bounds__(256) void scan_phase23(int* __restrict__ rowStart,
                                                    const int* __restrict__ blockSums,
                                                    int* __restrict__ cursor) {
    __shared__ int tmp[256];
    __shared__ int offs;
    const int t = threadIdx.x;
    int v = (t < SCAN_BLOCKS) ? blockSums[t] : 0;
    tmp[t] = v;
    __syncthreads();
#pragma unroll
    for (int off = 1; off < 256; off <<= 1) {
        int u = (t >= off) ? tmp[t - off] : 0;
        __syncthreads();
        tmp[t] += u;
        __syncthreads();
    }
    if (t == blockIdx.x) offs = tmp[t] - v;   // exclusive prefix for this block
    __syncthreads();
    const int i = blockIdx.x * 256 + t;
    if (i < N_NODES) {
        int val = rowStart[i] + offs;
        rowStart[i] = val;
        cursor[i] = val;
    }
}

// scatter edges into CSR order, packed {src, bits(w)}: one 8B store/edge
__global__ __launch_bounds__(256) void build_kernel(const int* __restrict__ src,
                                                    const int* __restrict__ dst,
                                                    const float* __restrict__ ew,
                                                    int* __restrict__ cursor,
                                                    int2* __restrict__ es2) {
    int e = blockIdx.x * 256 + threadIdx.x;
    if (e >= E_EDGES) return;
    int d = dst[e];
    int pos = atomicAdd(&cursor[d], 1);
    es2[pos] = make_int2(src[e], __float_as_int(ew[e]));
}

// ---------------------------------------------------------------------------
// Gather raw x: aggxh[n] = bf16( sum_e w_e * xh[src_e] )
// 16 lanes/node (16 B/lane), unroll-4 -> 16 independent load chains/wave.
// ---------------------------------------------------------------------------
__global__ __launch_bounds__(256) void gather_x_kernel(
        const ushort* __restrict__ xh, const int2* __restrict__ es2,
        const int* __restrict__ rowStart, const int* __restrict__ rowEnd,
        ushort* __restrict__ aggxh) {
    int gid = blockIdx.x * 256 + threadIdx.x;
    int node = gid >> 4;
    if (node >= N_NODES) return;
    int q = gid & 15;                     // elems [q*8, q*8+8)
    int e = rowStart[node], end = rowEnd[node];

    float sA[8] = {0,0,0,0,0,0,0,0};
    float sB[8] = {0,0,0,0,0,0,0,0};
    for (; e + 4 <= end; e += 4) {
        int2 m0 = es2[e], m1 = es2[e + 1], m2 = es2[e + 2], m3 = es2[e + 3];
        uint4 v0 = *(const uint4*)(xh + (size_t)m0.x * 128 + q * 8);
        uint4 v1 = *(const uint4*)(xh + (size_t)m1.x * 128 + q * 8);
        uint4 v2 = *(const uint4*)(xh + (size_t)m2.x * 128 + q * 8);
        uint4 v3 = *(const uint4*)(xh + (size_t)m3.x * 128 + q * 8);
        float w0 = __int_as_float(m0.y), w1 = __int_as_float(m1.y);
        float w2 = __int_as_float(m2.y), w3 = __int_as_float(m3.y);
        sA[0] = fmaf(w0, bflo(v0.x), sA[0]); sA[1] = fmaf(w0, bfhi(v0.x), sA[1]);
        sA[2] = fmaf(w0, bflo(v0.y), sA[2]); sA[3] = fmaf(w0, bfhi(v0.y), sA[3]);
        sA[4] = fmaf(w0, bflo(v0.z), sA[4]); sA[5] = fmaf(w0, bfhi(v0.z), sA[5]);
        sA[6] = fmaf(w0, bflo(v0.w), sA[6]); sA[7] = fmaf(w0, bfhi(v0.w), sA[7]);
        sB[0] = fmaf(w1, bflo(v1.x), sB[0]); sB[1] = fmaf(w1, bfhi(v1.x), sB[1]);
        sB[2] = fmaf(w1, bflo(v1.y), sB[2]); sB[3] = fmaf(w1, bfhi(v1.y), sB[3]);
        sB[4] = fmaf(w1, bflo(v1.z), sB[4]); sB[5] = fmaf(w1, bfhi(v1.z), sB[5]);
        sB[6] = fmaf(w1, bflo(v1.w), sB[6]); sB[7] = fmaf(w1, bfhi(v1.w), sB[7]);
        sA[0] = fmaf(w2, bflo(v2.x), sA[0]); sA[1] = fmaf(w2, bfhi(v2.x), sA[1]);
        sA[2] = fmaf(w2, bflo(v2.y), sA[2]); sA[3] = fmaf(w2, bfhi(v2.y), sA[3]);
        sA[4] = fmaf(w2, bflo(v2.z), sA[4]); sA[5] = fmaf(w2, bfhi(v2.z), sA[5]);
        sA[6] = fmaf(w2, bflo(v2.w), sA[6]); sA[7] = fmaf(w2, bfhi(v2.w), sA[7]);
        sB[0] = fmaf(w3, bflo(v3.x), sB[0]); sB[1] = fmaf(w3, bfhi(v3.x), sB[1]);
        sB[2] = fmaf(w3, bflo(v3.y), sB[2]); sB[3] = fmaf(w3, bfhi(v3.y), sB[3]);
        sB[4] = fmaf(w3, bflo(v3.z), sB[4]); sB[5] = fmaf(w3, bfhi(v3.z), sB[5]);
        sB[6] = fmaf(w3, bflo(v3.w), sB[6]); sB[7] = fmaf(w3, bfhi(v3.w), sB[7]);
    }
    for (; e < end; ++e) {
        int2 m = es2[e];
        float w = __int_as_float(m.y);
        uint4 v = *(const uint4*)(xh + (size_t)m.x * 128 + q * 8);
        sA[0] = fmaf(w, bflo(v.x), sA[0]); sA[1] = fmaf(w, bfhi(v.x), sA[1]);
        sA[2] = fmaf(w, bflo(v.y), sA[2]); sA[3] = fmaf(w, bfhi(v.y), sA[3]);
        sA[4] = fmaf(w, bflo(v.z), sA[4]); sA[5] = fmaf(w, bfhi(v.z), sA[5]);
        sA[6] = fmaf(w, bflo(v.w), sA[6]); sA[7] = fmaf(w, bfhi(v.w), sA[7]);
    }
    uint4 o;
    o.x = (uint)f2bf(sA[0] + sB[0]) | ((uint)f2bf(sA[1] + sB[1]) << 16);
    o.y = (uint)f2bf(sA[2] + sB[2]) | ((uint)f2bf(sA[3] + sB[3]) << 16);
    o.z = (uint)f2bf(sA[4] + sB[4]) | ((uint)f2bf(sA[5] + sB[5]) << 16);
    o.w = (uint)f2bf(sA[6] + sB[6]) | ((uint)f2bf(sA[7] + sB[7]) << 16);
    *(uint4*)(aggxh + (size_t)node * 128 + q * 8) = o;
}

// ---------------------------------------------------------------------------
// Readout (bf16 MFMA, no LDS): out = xh @ WoutH^T + b_out
// ---------------------------------------------------------------------------
__global__ __launch_bounds__(256) void out_gemm_bf16(const ushort* __restrict__ xh,
                                                     const ushort* __restrict__ WoutH,
                                                     const float* __restrict__ bout,
                                                     float* __restrict__ out, int M) {
    const int tid = threadIdx.x;
    const int lane = tid & 63;
    const int wv = tid >> 6;
    const int rowBase = blockIdx.x * 256 + wv * 64;
    const int l16 = lane & 15;
    const int q = lane >> 4;

    int rowIdx[4];
#pragma unroll
    for (int i = 0; i < 4; ++i) {
        int gr = rowBase + i * 16 + l16;
        rowIdx[i] = gr < M ? gr : M - 1;
    }

    v4f acc[4][3];
#pragma unroll
    for (int i = 0; i < 4; ++i)
#pragma unroll
        for (int j = 0; j < 3; ++j) { v4f z = {0.f,0.f,0.f,0.f}; acc[i][j] = z; }

#pragma unroll
    for (int ks = 0; ks < 4; ++ks) {
        const int kb = ks * 32 + q * 8;
        v8s a[4], b[3];
#pragma unroll
        for (int i = 0; i < 4; ++i)
            a[i] = *(const v8s*)(xh + (size_t)rowIdx[i] * 128 + kb);
#pragma unroll
        for (int j = 0; j < 3; ++j)
            b[j] = *(const v8s*)(WoutH + (size_t)(j * 16 + l16) * 128 + kb);
#pragma unroll
        for (int i = 0; i < 4; ++i)
#pragma unroll
            for (int j = 0; j < 3; ++j)
                acc[i][j] = __builtin_amdgcn_mfma_f32_16x16x32_bf16(a[i], b[j], acc[i][j], 0, 0, 0);
    }

#pragma unroll
    for (int j = 0; j < 3; ++j) {
        int col = j * 16 + l16;
        if (col >= OUT_DIM) continue;
        float bj = bout[col];
#pragma unroll
        for (int i = 0; i < 4; ++i) {
            int grB = rowBase + i * 16 + q * 4;
#pragma unroll
            for (int r = 0; r < 4; ++r) {
                int gr = grB + r;
                if (gr < M) out[(size_t)gr * OUT_DIM + col] = acc[i][j][r] + bj;
            }
        }
    }
}

extern "C" void kernel_launch(void* const* d_in, const int* in_sizes, int n_in,
                              void* d_out, int out_size, void* d_ws, size_t ws_size,
                              hipStream_t stream) {
    const float* x_in   = (const float*)d_in[0];
    const int*   ei     = (const int*)  d_in[1];   // (2,E) int32: src=ei, dst=ei+E
    const float* ew     = (const float*)d_in[2];
    const float* W_emb  = (const float*)d_in[3];
    const float* b_emb  = (const float*)d_in[4];
    const float* W_lin  = (const float*)d_in[5];
    const float* W_anti = (const float*)d_in[6];
    const float* b_conv = (const float*)d_in[7];
    const float* W_out  = (const float*)d_in[8];
    const float* b_out  = (const float*)d_in[9];
    float* out = (float*)d_out;

    // workspace: xh(bf16) | aggxh(bf16) | WembH | Wcat2H | WoutH |
    //            rowStart | cursor | es2(int2) | blockSums    (~31 MB)
    ushort* xh     = (ushort*)d_ws;
    ushort* aggxh  = xh + (size_t)N_NODES * D_DIM;
    ushort* WembH  = aggxh + (size_t)N_NODES * D_DIM;
    ushort* Wcat2H = WembH + D_DIM * D_DIM;
    ushort* WoutH  = Wcat2H + 2 * D_DIM * D_DIM;
    int*    rowStart = (int*)(WoutH + 48 * D_DIM);
    int*    cursor   = rowStart + N_NODES;
    int2*   es2      = (int2*)(cursor + N_NODES);
    int*    blockSums = (int*)(es2 + E_EDGES);

    const int* src = ei;
    const int* dst = ei + E_EDGES;
    const int edgeBlocks = (E_EDGES + 255) / 256;
    const int gemmBlocksX = (N_NODES + 127) / 128;       // 391

    // ---- CSR build + weight prep (once; structure is iteration-invariant) ----
    zero_prep_kernel<<<SCAN_BLOCKS, 256, 0, stream>>>(cursor, W_emb, W_lin, W_anti,
                                                      W_out, WembH, Wcat2H, WoutH);
    hist_kernel<<<edgeBlocks, 256, 0, stream>>>(dst, cursor);
    scan_phase1<<<SCAN_BLOCKS, 256, 0, stream>>>(cursor, rowStart, blockSums);
    scan_phase23<<<SCAN_BLOCKS, 256, 0, stream>>>(rowStart, blockSums, cursor);
    build_kernel<<<edgeBlocks, 256, 0, stream>>>(src, dst, ew, cursor, es2);
    // after build: cursor[d] == row end offset

    // ---- embed (bf16 state only) ----
    mfma_embed_gemm<<<gemmBlocksX, 256, 0, stream>>>(x_in, WembH, b_emb, xh, N_NODES);

    // ---- iterations: gather + conv GEMM (bf16 in-place state) ----
    for (int it = 0; it < N_ITERS; ++it) {
        gather_x_kernel<<<(N_NODES * 16 + 255) / 256, 256, 0, stream>>>(
            xh, es2, rowStart, cursor, aggxh);
        mfma_conv_update<<<gemmBlocksX, 256, 0, stream>>>(
            xh, aggxh, Wcat2H, b_conv, N_NODES);
    }
    // ---- readout from final xh (bf16 MFMA) ----
    out_gemm_bf16<<<(N_NODES + 255) / 256, 256, 0, stream>>>(xh, WoutH, b_out, out, N_NODES);
}

// Round 10
// 443.038 us; speedup vs baseline: 1.2674x; 1.0263x over previous
//
#include <hip/hip_runtime.h>
#include <math.h>

#define N_NODES 50000
#define E_EDGES 600000
#define D_DIM 128
#define OUT_DIM 40
#define N_ITERS 5
#define GAMMA_C 0.1f
#define EPS_C 0.1f
#define SCAN_BLOCKS 196          // 196*256 = 50176 >= N_NODES
#define GEMM_BLOCKS 391          // ceil(50000/128)
#define EDGE_BLOCKS 2344         // ceil(600000/256)

typedef short v8s __attribute__((ext_vector_type(8)));   // 8 bf16 (4 VGPRs)
typedef float v4f __attribute__((ext_vector_type(4)));   // MFMA accumulator
typedef unsigned int uint;
typedef unsigned short ushort;

__device__ __forceinline__ ushort f2bf(float f) {        // RNE fp32->bf16
    union { float f; uint u; } v; v.f = f;
    uint u = v.u;
    uint r = 0x7fffu + ((u >> 16) & 1u);
    return (ushort)((u + r) >> 16);
}
__device__ __forceinline__ float bf2f(ushort h) {
    union { uint u; float f; } v; v.u = ((uint)h) << 16;
    return v.f;
}
__device__ __forceinline__ float bflo(uint u) {
    union { uint u; float f; } v; v.u = u << 16; return v.f;
}
__device__ __forceinline__ float bfhi(uint u) {
    union { uint u; float f; } v; v.u = u & 0xffff0000u; return v.f;
}

// ---------------------------------------------------------------------------
// Combined (once): zero cursor[N] + weight prep to bf16.
// Wcat2[c][k] (row-stride 256): k<128 -> A[c][k]=Wanti[c][k]-Wanti[k][c]-g*I,
//                               k>=128 -> W_lin[c][k-128]
// WoutH: 48x128 bf16 (rows 40..47 zero-padded)
// ---------------------------------------------------------------------------
__global__ __launch_bounds__(256) void zero_prep_kernel(int* __restrict__ cursor,
                                                        const float* __restrict__ Wemb,
                                                        const float* __restrict__ Wlin,
                                                        const float* __restrict__ Wanti,
                                                        const float* __restrict__ Wout,
                                                        ushort* __restrict__ WembH,
                                                        ushort* __restrict__ Wcat2H,
                                                        ushort* __restrict__ WoutH) {
    int i = blockIdx.x * 256 + threadIdx.x;
    if (i < N_NODES) cursor[i] = 0;
    if (i < D_DIM * D_DIM) {
        int r = i >> 7, c = i & 127;
        WembH[i] = f2bf(Wemb[i]);
        float a = Wanti[r * 128 + c] - Wanti[c * 128 + r];
        if (r == c) a -= GAMMA_C;
        Wcat2H[r * 256 + c]       = f2bf(a);
        Wcat2H[r * 256 + 128 + c] = f2bf(Wlin[r * 128 + c]);
        if (i < 48 * 128) WoutH[i] = (r < OUT_DIM) ? f2bf(Wout[r * 128 + c]) : (ushort)0;
    }
}

// ---------------------------------------------------------------------------
// MERGED: embed GEMM (blocks [0,391)) + CSR build scatter (blocks [391,2735)).
// embed is independent of the CSR chain -> overlaps under build's atomics.
// embed: xh = bf16(x0 @ W_emb^T + b_emb); hybrid LDS (A staged, W global).
// build: es2[pos] = {src, bits(w)} at pos = cursor[dst]++ (one 8B store/edge).
// Fragments (verified m89/m120): A[m=lane&15][k=quad*8+j],
// B[n=lane&15][k=quad*8+j], C/D: col=lane&15, row=quad*4+reg.
// ---------------------------------------------------------------------------
__global__ __launch_bounds__(256) void build_embed_kernel(
        const float* __restrict__ Xf, const ushort* __restrict__ Wh,
        const float* __restrict__ bias, ushort* __restrict__ xH,
        const int* __restrict__ src, const int* __restrict__ dst,
        const float* __restrict__ ew, int* __restrict__ cursor,
        int2* __restrict__ es2, int M) {
    __shared__ ushort Xs[128 * 128];          // 32 KB (embed blocks only)
    const int tid = threadIdx.x;

    if (blockIdx.x >= GEMM_BLOCKS) {
        // ---- build role ----
        int e = (blockIdx.x - GEMM_BLOCKS) * 256 + tid;
        if (e < E_EDGES) {
            int d = dst[e];
            int pos = atomicAdd(&cursor[d], 1);
            es2[pos] = make_int2(src[e], __float_as_int(ew[e]));
        }
        return;
    }

    // ---- embed role ----
    const int rowBase = blockIdx.x * 128;
#pragma unroll
    for (int p = 0; p < 8; ++p) {
        int cid = p * 256 + tid;
        int r = cid >> 4, c8 = cid & 15;
        int gr = rowBase + r;
        uint4 val = make_uint4(0, 0, 0, 0);
        if (gr < M) {
            const float* ptr = Xf + (size_t)gr * 128 + c8 * 8;
            float4 f0 = *(const float4*)ptr;
            float4 f1 = *(const float4*)(ptr + 4);
            val.x = (uint)f2bf(f0.x) | ((uint)f2bf(f0.y) << 16);
            val.y = (uint)f2bf(f0.z) | ((uint)f2bf(f0.w) << 16);
            val.z = (uint)f2bf(f1.x) | ((uint)f2bf(f1.y) << 16);
            val.w = (uint)f2bf(f1.z) | ((uint)f2bf(f1.w) << 16);
        }
        *(uint4*)(Xs + r * 128 + ((c8 ^ (r & 7)) << 3)) = val;
    }
    __syncthreads();

    const int lane = tid & 63;
    const int wv = tid >> 6;
    const int wrow = (wv & 1) * 64;
    const int wcol = (wv >> 1) * 64;
    const int l16 = lane & 15;
    const int q = lane >> 4;

    v4f acc[4][4];
#pragma unroll
    for (int i = 0; i < 4; ++i)
#pragma unroll
        for (int j = 0; j < 4; ++j) { v4f z = {0.f,0.f,0.f,0.f}; acc[i][j] = z; }

#pragma unroll
    for (int ks = 0; ks < 4; ++ks) {
        const int chunk = ks * 4 + q;
        v8s a[4], b[4];
#pragma unroll
        for (int i = 0; i < 4; ++i) {
            int m = wrow + i * 16 + l16;
            a[i] = *(const v8s*)(Xs + m * 128 + ((chunk ^ (m & 7)) << 3));
        }
#pragma unroll
        for (int j = 0; j < 4; ++j)
            b[j] = *(const v8s*)(Wh + (size_t)(wcol + j * 16 + l16) * 128 + chunk * 8);
#pragma unroll
        for (int i = 0; i < 4; ++i)
#pragma unroll
            for (int j = 0; j < 4; ++j)
                acc[i][j] = __builtin_amdgcn_mfma_f32_16x16x32_bf16(a[i], b[j], acc[i][j], 0, 0, 0);
    }

#pragma unroll
    for (int j = 0; j < 4; ++j) {
        int col = wcol + j * 16 + l16;
        float bj = bias[col];
#pragma unroll
        for (int i = 0; i < 4; ++i) {
            int grB = rowBase + wrow + i * 16 + q * 4;
#pragma unroll
            for (int r = 0; r < 4; ++r) {
                int gr = grB + r;
                if (gr < M) xH[(size_t)gr * 128 + col] = f2bf(acc[i][j][r] + bj);
            }
        }
    }
}

// ---------------------------------------------------------------------------
// conv GEMM + update (bf16 state, hybrid LDS):
//   conv = aggxh@W_lin^T + xh@A^T + b_conv    (two staged K=128 chunks)
//   xh  += bf16( eps*tanh(conv) )             (x-old read from LDS tile!)
// doOut (last iter): epilogue writes updated bf16 back into the LDS tile,
// then computes out = xh_new @ Wout^T + b_out from LDS (waves = row quarters).
// ---------------------------------------------------------------------------
__global__ __launch_bounds__(256) void mfma_conv_update(
        ushort* __restrict__ xh, const ushort* __restrict__ aggxh,
        const ushort* __restrict__ Wcat2, const float* __restrict__ bconv,
        const ushort* __restrict__ WoutH, const float* __restrict__ bout,
        float* __restrict__ out, int doOut, int M) {
    __shared__ ushort Xs[128 * 128];          // 32 KB, reused per chunk
    const int tid = threadIdx.x;
    const int rowBase = blockIdx.x * 128;
    const int lane = tid & 63;
    const int wv = tid >> 6;
    const int wrow = (wv & 1) * 64;
    const int wcol = (wv >> 1) * 64;
    const int l16 = lane & 15;
    const int q = lane >> 4;

    v4f acc[4][4];
#pragma unroll
    for (int i = 0; i < 4; ++i)
#pragma unroll
        for (int j = 0; j < 4; ++j) { v4f z = {0.f,0.f,0.f,0.f}; acc[i][j] = z; }

#pragma unroll
    for (int kc = 0; kc < 2; ++kc) {
        // kc=0: A-src = aggxh, W chunk = W_lin (k in [128,256))
        // kc=1: A-src = xh,    W chunk = A     (k in [0,128))
        const ushort* Xsrc = kc ? xh : aggxh;
        const int wOff = kc ? 0 : 128;
        if (kc) __syncthreads();              // all reads of chunk0 done
#pragma unroll
        for (int p = 0; p < 8; ++p) {
            int cid = p * 256 + tid;
            int r = cid >> 4, c8 = cid & 15;
            int gr = rowBase + r;
            uint4 xv = make_uint4(0, 0, 0, 0);
            if (gr < M) xv = *(const uint4*)(Xsrc + (size_t)gr * 128 + c8 * 8);
            *(uint4*)(Xs + r * 128 + ((c8 ^ (r & 7)) << 3)) = xv;
        }
        __syncthreads();

#pragma unroll
        for (int ks = 0; ks < 4; ++ks) {
            const int chunk = ks * 4 + q;
            v8s a[4], b[4];
#pragma unroll
            for (int i = 0; i < 4; ++i) {
                int m = wrow + i * 16 + l16;
                a[i] = *(const v8s*)(Xs + m * 128 + ((chunk ^ (m & 7)) << 3));
            }
#pragma unroll
            for (int j = 0; j < 4; ++j)
                b[j] = *(const v8s*)(Wcat2 + (size_t)(wcol + j * 16 + l16) * 256 + wOff + chunk * 8);
#pragma unroll
            for (int i = 0; i < 4; ++i)
#pragma unroll
                for (int j = 0; j < 4; ++j)
                    acc[i][j] = __builtin_amdgcn_mfma_f32_16x16x32_bf16(a[i], b[j], acc[i][j], 0, 0, 0);
        }
    }

    // epilogue: x-old comes from the LDS tile (Xs holds this block's xh rows).
#pragma unroll
    for (int j = 0; j < 4; ++j) {
        int col = wcol + j * 16 + l16;
        float bj = bconv[col];
        const int csw = col >> 3, clo = col & 7;
#pragma unroll
        for (int i = 0; i < 4; ++i) {
            int trB = wrow + i * 16 + q * 4;
#pragma unroll
            for (int r = 0; r < 4; ++r) {
                int tr = trB + r;
                int gr = rowBase + tr;
                if (gr < M) {
                    int li = tr * 128 + (((csw ^ (tr & 7)) << 3) | clo);
                    float conv = acc[i][j][r] + bj;
                    float xv = bf2f(Xs[li]) + EPS_C * tanhf(conv);
                    ushort h = f2bf(xv);
                    xh[(size_t)gr * 128 + col] = h;
                    if (doOut) Xs[li] = h;     // refresh tile for fused readout
                }
            }
        }
    }

    if (doOut) {
        __syncthreads();                       // tile now holds xh_new
        // out phase: waves take row-quarters (32 rows each), 48 padded cols
        v4f acc2[2][3];
#pragma unroll
        for (int i = 0; i < 2; ++i)
#pragma unroll
            for (int j = 0; j < 3; ++j) { v4f z = {0.f,0.f,0.f,0.f}; acc2[i][j] = z; }

#pragma unroll
        for (int ks = 0; ks < 4; ++ks) {
            const int chunk = ks * 4 + q;
            v8s a2[2], b2[3];
#pragma unroll
            for (int i = 0; i < 2; ++i) {
                int m = wv * 32 + i * 16 + l16;
                a2[i] = *(const v8s*)(Xs + m * 128 + ((chunk ^ (m & 7)) << 3));
            }
#pragma unroll
            for (int j = 0; j < 3; ++j)
                b2[j] = *(const v8s*)(WoutH + (size_t)(j * 16 + l16) * 128 + chunk * 8);
#pragma unroll
            for (int i = 0; i < 2; ++i)
#pragma unroll
                for (int j = 0; j < 3; ++j)
                    acc2[i][j] = __builtin_amdgcn_mfma_f32_16x16x32_bf16(a2[i], b2[j], acc2[i][j], 0, 0, 0);
        }

#pragma unroll
        for (int j = 0; j < 3; ++j) {
            int col = j * 16 + l16;
            if (col >= OUT_DIM) continue;
            float bj = bout[col];
#pragma unroll
            for (int i = 0; i < 2; ++i) {
                int grB = rowBase + wv * 32 + i * 16 + q * 4;
#pragma unroll
                for (int r = 0; r < 4; ++r) {
                    int gr = grB + r;
                    if (gr < M) out[(size_t)gr * OUT_DIM + col] = acc2[i][j][r] + bj;
                }
            }
        }
    }
}

// ---------------------------------------------------------------------------
// CSR build (once per launch; edge structure is iteration-invariant)
// ---------------------------------------------------------------------------
__global__ __launch_bounds__(256) void hist_kernel(const int* __restrict__ dst,
                                                   int* __restrict__ cnt) {
    int e = blockIdx.x * 256 + threadIdx.x;
    if (e < E_EDGES) atomicAdd(&cnt[dst[e]], 1);
}

__global__ __launch_bounds__(256) void scan_phase1(const int* __restrict__ deg,
                                                   int* __restrict__ localEx,
                                                   int* __restrict__ blockSums) {
    __shared__ int tmp[256];
    const int t = threadIdx.x;
    const int i = blockIdx.x * 256 + t;
    int v = (i < N_NODES) ? deg[i] : 0;
    tmp[t] = v;
    __syncthreads();
#pragma unroll
    for (int off = 1; off < 256; off <<= 1) {
        int u = (t >= off) ? tmp[t - off] : 0;
        __syncthreads();
        tmp[t] += u;
        __syncthreads();
    }
    if (i < N_NODES) localEx[i] = tmp[t] - v;
    if (t == 255) blockSums[blockIdx.x] = tmp[255];
}

// merged phase2+3: every block redundantly scans the 196 block sums (read-only),
// picks its own exclusive offset, finalizes rowStart + cursor.
__global__ __launch_bounds__(256) void scan_phase23(int* __restrict__ rowStart,
                                                    const int* __restrict__ blockSums,
                                                    int* __restrict__ cursor) {
    __shared__ int tmp[256];
    __shared__ int offs;
    const int t = threadIdx.x;
    int v = (t < SCAN_BLOCKS) ? blockSums[t] : 0;
    tmp[t] = v;
    __syncthreads();
#pragma unroll
    for (int off = 1; off < 256; off <<= 1) {
        int u = (t >= off) ? tmp[t - off] : 0;
        __syncthreads();
        tmp[t] += u;
        __syncthreads();
    }
    if (t == blockIdx.x) offs = tmp[t] - v;
    __syncthreads();
    const int i = blockIdx.x * 256 + t;
    if (i < N_NODES) {
        int val = rowStart[i] + offs;
        rowStart[i] = val;
        cursor[i] = val;
    }
}

// ---------------------------------------------------------------------------
// Gather raw x: aggxh[n] = bf16( sum_e w_e * xh[src_e] )
// 16 lanes/node (16 B/lane), unroll-4 -> 16 independent load chains/wave.
// ---------------------------------------------------------------------------
__global__ __launch_bounds__(256) void gather_x_kernel(
        const ushort* __restrict__ xh, const int2* __restrict__ es2,
        const int* __restrict__ rowStart, const int* __restrict__ rowEnd,
        ushort* __restrict__ aggxh) {
    int gid = blockIdx.x * 256 + threadIdx.x;
    int node = gid >> 4;
    if (node >= N_NODES) return;
    int q = gid & 15;                     // elems [q*8, q*8+8)
    int e = rowStart[node], end = rowEnd[node];

    float sA[8] = {0,0,0,0,0,0,0,0};
    float sB[8] = {0,0,0,0,0,0,0,0};
    for (; e + 4 <= end; e += 4) {
        int2 m0 = es2[e], m1 = es2[e + 1], m2 = es2[e + 2], m3 = es2[e + 3];
        uint4 v0 = *(const uint4*)(xh + (size_t)m0.x * 128 + q * 8);
        uint4 v1 = *(const uint4*)(xh + (size_t)m1.x * 128 + q * 8);
        uint4 v2 = *(const uint4*)(xh + (size_t)m2.x * 128 + q * 8);
        uint4 v3 = *(const uint4*)(xh + (size_t)m3.x * 128 + q * 8);
        float w0 = __int_as_float(m0.y), w1 = __int_as_float(m1.y);
        float w2 = __int_as_float(m2.y), w3 = __int_as_float(m3.y);
        sA[0] = fmaf(w0, bflo(v0.x), sA[0]); sA[1] = fmaf(w0, bfhi(v0.x), sA[1]);
        sA[2] = fmaf(w0, bflo(v0.y), sA[2]); sA[3] = fmaf(w0, bfhi(v0.y), sA[3]);
        sA[4] = fmaf(w0, bflo(v0.z), sA[4]); sA[5] = fmaf(w0, bfhi(v0.z), sA[5]);
        sA[6] = fmaf(w0, bflo(v0.w), sA[6]); sA[7] = fmaf(w0, bfhi(v0.w), sA[7]);
        sB[0] = fmaf(w1, bflo(v1.x), sB[0]); sB[1] = fmaf(w1, bfhi(v1.x), sB[1]);
        sB[2] = fmaf(w1, bflo(v1.y), sB[2]); sB[3] = fmaf(w1, bfhi(v1.y), sB[3]);
        sB[4] = fmaf(w1, bflo(v1.z), sB[4]); sB[5] = fmaf(w1, bfhi(v1.z), sB[5]);
        sB[6] = fmaf(w1, bflo(v1.w), sB[6]); sB[7] = fmaf(w1, bfhi(v1.w), sB[7]);
        sA[0] = fmaf(w2, bflo(v2.x), sA[0]); sA[1] = fmaf(w2, bfhi(v2.x), sA[1]);
        sA[2] = fmaf(w2, bflo(v2.y), sA[2]); sA[3] = fmaf(w2, bfhi(v2.y), sA[3]);
        sA[4] = fmaf(w2, bflo(v2.z), sA[4]); sA[5] = fmaf(w2, bfhi(v2.z), sA[5]);
        sA[6] = fmaf(w2, bflo(v2.w), sA[6]); sA[7] = fmaf(w2, bfhi(v2.w), sA[7]);
        sB[0] = fmaf(w3, bflo(v3.x), sB[0]); sB[1] = fmaf(w3, bfhi(v3.x), sB[1]);
        sB[2] = fmaf(w3, bflo(v3.y), sB[2]); sB[3] = fmaf(w3, bfhi(v3.y), sB[3]);
        sB[4] = fmaf(w3, bflo(v3.z), sB[4]); sB[5] = fmaf(w3, bfhi(v3.z), sB[5]);
        sB[6] = fmaf(w3, bflo(v3.w), sB[6]); sB[7] = fmaf(w3, bfhi(v3.w), sB[7]);
    }
    for (; e < end; ++e) {
        int2 m = es2[e];
        float w = __int_as_float(m.y);
        uint4 v = *(const uint4*)(xh + (size_t)m.x * 128 + q * 8);
        sA[0] = fmaf(w, bflo(v.x), sA[0]); sA[1] = fmaf(w, bfhi(v.x), sA[1]);
        sA[2] = fmaf(w, bflo(v.y), sA[2]); sA[3] = fmaf(w, bfhi(v.y), sA[3]);
        sA[4] = fmaf(w, bflo(v.z), sA[4]); sA[5] = fmaf(w, bfhi(v.z), sA[5]);
        sA[6] = fmaf(w, bflo(v.w), sA[6]); sA[7] = fmaf(w, bfhi(v.w), sA[7]);
    }
    uint4 o;
    o.x = (uint)f2bf(sA[0] + sB[0]) | ((uint)f2bf(sA[1] + sB[1]) << 16);
    o.y = (uint)f2bf(sA[2] + sB[2]) | ((uint)f2bf(sA[3] + sB[3]) << 16);
    o.z = (uint)f2bf(sA[4] + sB[4]) | ((uint)f2bf(sA[5] + sB[5]) << 16);
    o.w = (uint)f2bf(sA[6] + sB[6]) | ((uint)f2bf(sA[7] + sB[7]) << 16);
    *(uint4*)(aggxh + (size_t)node * 128 + q * 8) = o;
}

extern "C" void kernel_launch(void* const* d_in, const int* in_sizes, int n_in,
                              void* d_out, int out_size, void* d_ws, size_t ws_size,
                              hipStream_t stream) {
    const float* x_in   = (const float*)d_in[0];
    const int*   ei     = (const int*)  d_in[1];   // (2,E) int32: src=ei, dst=ei+E
    const float* ew     = (const float*)d_in[2];
    const float* W_emb  = (const float*)d_in[3];
    const float* b_emb  = (const float*)d_in[4];
    const float* W_lin  = (const float*)d_in[5];
    const float* W_anti = (const float*)d_in[6];
    const float* b_conv = (const float*)d_in[7];
    const float* W_out  = (const float*)d_in[8];
    const float* b_out  = (const float*)d_in[9];
    float* out = (float*)d_out;

    // workspace: xh(bf16) | aggxh(bf16) | WembH | Wcat2H | WoutH |
    //            rowStart | cursor | es2(int2) | blockSums    (~31 MB)
    ushort* xh     = (ushort*)d_ws;
    ushort* aggxh  = xh + (size_t)N_NODES * D_DIM;
    ushort* WembH  = aggxh + (size_t)N_NODES * D_DIM;
    ushort* Wcat2H = WembH + D_DIM * D_DIM;
    ushort* WoutH  = Wcat2H + 2 * D_DIM * D_DIM;
    int*    rowStart = (int*)(WoutH + 48 * D_DIM);
    int*    cursor   = rowStart + N_NODES;
    int2*   es2      = (int2*)(cursor + N_NODES);
    int*    blockSums = (int*)(es2 + E_EDGES);

    const int* src = ei;
    const int* dst = ei + E_EDGES;

    // ---- CSR chain + weight prep ----
    zero_prep_kernel<<<SCAN_BLOCKS, 256, 0, stream>>>(cursor, W_emb, W_lin, W_anti,
                                                      W_out, WembH, Wcat2H, WoutH);
    hist_kernel<<<EDGE_BLOCKS, 256, 0, stream>>>(dst, cursor);
    scan_phase1<<<SCAN_BLOCKS, 256, 0, stream>>>(cursor, rowStart, blockSums);
    scan_phase23<<<SCAN_BLOCKS, 256, 0, stream>>>(rowStart, blockSums, cursor);
    // ---- build (CSR scatter) + embed GEMM, role-split & overlapped ----
    build_embed_kernel<<<GEMM_BLOCKS + EDGE_BLOCKS, 256, 0, stream>>>(
        x_in, WembH, b_emb, xh, src, dst, ew, cursor, es2, N_NODES);
    // after build: cursor[d] == row end offset

    // ---- iterations: gather + conv GEMM (bf16 in-place state); last conv
    //      fuses the readout ----
    for (int it = 0; it < N_ITERS; ++it) {
        gather_x_kernel<<<(N_NODES * 16 + 255) / 256, 256, 0, stream>>>(
            xh, es2, rowStart, cursor, aggxh);
        mfma_conv_update<<<GEMM_BLOCKS, 256, 0, stream>>>(
            xh, aggxh, Wcat2H, b_conv, WoutH, b_out, out,
            (it == N_ITERS - 1) ? 1 : 0, N_NODES);
    }
}